// Round 11
// baseline (569.158 us; speedup 1.0000x reference)
//
#include <hip/hip_runtime.h>
#include <math.h>

#define T 8
#define N 20000
#define E 320000
#define EPS 1e-5f
#define NB 32          // item-sort blocks per t: 16 agg-half + 16 w-half
#define CHUNK 20000    // E/16 items per block
#define NPACK 10000    // N/2 packed u32 (2 x u16 counters)

__device__ __forceinline__ float sigm(float x) { return 1.0f / (1.0f + expf(-x)); }

// ---------------------------------------------------------------------------
// K1: per-(t,block) LDS histogram of item keys. Blocks 0..15 histogram dst
// over agg items; blocks 16..31 histogram src over w items.
__global__ __launch_bounds__(1024) void k_hist(const int* __restrict__ edges,
                                               unsigned int* __restrict__ hist_g) {
    __shared__ unsigned int h32[NPACK];
    const int t = blockIdx.x, b = blockIdx.y;
    const int tid = threadIdx.x;
    for (int i = tid; i < NPACK; i += 1024) h32[i] = 0;
    __syncthreads();
    const bool isAgg = (b < 16);
    const int cs = (isAgg ? b : b - 16) * CHUNK;
    const int* keys = edges + (size_t)t * 2 * E + (isAgg ? E : 0) + cs;
    for (int i = tid; i < CHUNK; i += 1024) {
        int k = keys[i];
        atomicAdd(&h32[k >> 1], 1u << ((k & 1) * 16));
    }
    __syncthreads();
    unsigned int* out = hist_g + (size_t)(t * NB + b) * NPACK;
    for (int i = tid; i < NPACK; i += 1024) out[i] = h32[i];
}

// K2a: column sum over the 32 blocks — one thread per packed key pair.
__global__ __launch_bounds__(256) void k_colsum(
    const unsigned int* __restrict__ hist_g, int* __restrict__ tot,
    int* __restrict__ dega, float* __restrict__ dinv) {
    int idx = blockIdx.x * 256 + threadIdx.x;
    if (idx >= T * NPACK) return;
    int t = idx / NPACK, i = idx - t * NPACK;
    const unsigned int* hp = hist_g + (size_t)t * NB * NPACK + i;
    unsigned int a0 = 0, a1 = 0, w0 = 0, w1 = 0;
#pragma unroll
    for (int b = 0; b < 16; b++) {
        unsigned int h = hp[(size_t)b * NPACK];
        a0 += h & 0xffffu; a1 += h >> 16;
    }
#pragma unroll
    for (int b = 16; b < 32; b++) {
        unsigned int h = hp[(size_t)b * NPACK];
        w0 += h & 0xffffu; w1 += h >> 16;
    }
    int n0 = t * N + 2 * i;
    tot[n0]     = (int)(a0 + w0);
    tot[n0 + 1] = (int)(a1 + w1);
    dega[n0]     = (int)a0;
    dega[n0 + 1] = (int)a1;
    dinv[n0]     = rsqrtf((float)a0 + 1.0f);
    dinv[n0 + 1] = rsqrtf((float)a1 + 1.0f);
}

// K2b: per-t exclusive prefix over 20000 node totals -> offs (+ sentinel).
__global__ __launch_bounds__(1024) void k_scanN(const int* __restrict__ tot,
                                                int* __restrict__ offs) {
    const int t = blockIdx.x, tid = threadIdx.x;
    __shared__ int sh[1024];
    int local[20];
    int sum = 0;
    if (tid < 1000) {
        const int* tp = tot + t * N + tid * 20;
#pragma unroll
        for (int i = 0; i < 20; i++) { local[i] = tp[i]; sum += local[i]; }
    }
    sh[tid] = sum;
    __syncthreads();
    for (int off = 1; off < 1024; off <<= 1) {
        int v = (tid >= off) ? sh[tid - off] : 0;
        __syncthreads();
        sh[tid] += v;
        __syncthreads();
    }
    if (tid < 1000) {
        int run = t * 2 * E + sh[tid] - sum;
        int* op = offs + t * N + tid * 20;
#pragma unroll
        for (int i = 0; i < 20; i++) { op[i] = run; run += local[i]; }
    }
    if (t == T - 1 && tid == 0) offs[T * N] = 2 * T * E;
}

// K2c: per-node running prefix over the 32 blocks -> base_g.
__global__ __launch_bounds__(256) void k_base(
    const unsigned int* __restrict__ hist_g, const int* __restrict__ offs,
    unsigned int* __restrict__ base_g) {
    int node = blockIdx.x * 256 + threadIdx.x;
    if (node >= T * N) return;
    int t = node / N, n = node - t * N;
    const unsigned short* h16 = (const unsigned short*)hist_g;
    int run = offs[node];
#pragma unroll
    for (int b = 0; b < NB; b++) {
        size_t o = (size_t)(t * NB + b) * N + n;
        base_g[o] = (unsigned int)run;
        run += h16[o];
    }
}

// K2d: fold dinv into x IN PLACE: x[t][n][:] *= dinv[t][n]. Legal: harness
// restores d_in from pristine copies before every launch.
__global__ __launch_bounds__(256) void k_scale(float* __restrict__ x,
                                               const float* __restrict__ dinv) {
    int idx = blockIdx.x * 256 + threadIdx.x;   // one float4 per thread
    if (idx >= T * N * 16) return;
    float d = dinv[idx >> 4];
    float4* xp = (float4*)x;
    float4 vv = xp[idx];
    vv.x *= d; vv.y *= d; vv.z *= d; vv.w *= d;
    xp[idx] = vv;
}

// K3: fill. Position = global per-(block,key) base + LDS u16 running count.
// One 4B scattered write per item:
//   agg item -> eidx = src*64 (pre-scaled float row offset)
//   w   item -> eidx = float bits of dinv[dst]
__global__ __launch_bounds__(1024) void k_fill(const int* __restrict__ edges,
                                               const unsigned int* __restrict__ base_g,
                                               const float* __restrict__ dinv,
                                               int* __restrict__ eidx) {
    __shared__ unsigned int c32[NPACK];
    const int t = blockIdx.x, b = blockIdx.y;
    const int tid = threadIdx.x;
    for (int i = tid; i < NPACK; i += 1024) c32[i] = 0;
    __syncthreads();
    const bool isAgg = (b < 16);
    const int cs = (isAgg ? b : b - 16) * CHUNK;
    const int* keys = edges + (size_t)t * 2 * E + (isAgg ? E : 0) + cs;
    const int* pays = edges + (size_t)t * 2 * E + (isAgg ? 0 : E) + cs;
    const unsigned int* base = base_g + (size_t)(t * NB + b) * N;
    const float* dv = dinv + t * N;
    if (isAgg) {
        for (int i = tid; i < CHUNK; i += 1024) {
            int k = keys[i];
            int p = pays[i];
            unsigned int sh = (unsigned int)((k & 1) * 16);
            unsigned int old = atomicAdd(&c32[k >> 1], 1u << sh);
            unsigned int cnt = (old >> sh) & 0xffffu;
            eidx[base[k] + cnt] = p << 6;
        }
    } else {
        for (int i = tid; i < CHUNK; i += 1024) {
            int k = keys[i];
            int p = pays[i];
            unsigned int sh = (unsigned int)((k & 1) * 16);
            unsigned int old = atomicAdd(&c32[k >> 1], 1u << sh);
            unsigned int cnt = (old >> sh) & 0xffffu;
            eidx[base[k] + cnt] = __float_as_int(dv[p]);
        }
    }
}

// K4: fused gather + layer-1 GEMM + BN/ReLU + alpha-pool partial.
// 1024 threads = 16 waves = 16 nodes. Wave w gathers node nb+w (R8-style
// scalar 4-unrolled loop: 4 independent loads in flight), stores operand to
// LDS vL[w]. After one barrier, thread (nl=tid>>6, j=tid&63) computes output
// features j and j+64 from transposed W1 (LDS, pad 68 keeps float4 rows
// conflict-free), applies BN/ReLU/alpha, reduces over the 16 nodes, and
// writes one coalesced 128-float partial per block. No global v/alpha.
// t = blockIdx&7 keeps each XCD on one t's x-slice.
__global__ __launch_bounds__(1024) void k_gather_gemm(
    const int* __restrict__ eidx, const int* __restrict__ offs,
    const int* __restrict__ dega, const float* __restrict__ dinv,
    const float* __restrict__ xs,
    const float* __restrict__ W1, const float* __restrict__ b1,
    const float* __restrict__ g1, const float* __restrict__ be1,
    const float* __restrict__ m1, const float* __restrict__ v1,
    float* __restrict__ partial) {
    __shared__ float Wt[128][68];      // W1 transposed [j][k], padded row
    __shared__ float vL[16][64];
    __shared__ float al[16];
    __shared__ float sb[128], st[128];
    __shared__ float part[16][128];
    const int tid = threadIdx.x;
    const int t = blockIdx.x & 7;
    const int nb = (blockIdx.x >> 3) << 4;     // base node within t

    for (int i = tid; i < 8192; i += 1024) {
        Wt[i & 127][i >> 7] = W1[i];
    }
    if (tid < 128) {
        float s = g1[tid] * rsqrtf(v1[tid] + EPS);
        sb[tid] = s;
        st[tid] = s * b1[tid] + be1[tid] - m1[tid] * s;
    }

    // ---- gather phase (per wave, intra-wave LDS only; no barrier needed) --
    const int w = tid >> 6, lane = tid & 63;
    const int n = nb + w;
    const int node = t * N + n;
    int start = offs[node];
    int end = offs[node + 1];
    int na = dega[node];
    const float* xt = xs + (size_t)t * N * 64;
    float acc = 0.f;
    int e = start, stop4 = start + (na & ~3);
    for (; e < stop4; e += 4) {
        int o0 = __builtin_nontemporal_load(&eidx[e + 0]);
        int o1 = __builtin_nontemporal_load(&eidx[e + 1]);
        int o2 = __builtin_nontemporal_load(&eidx[e + 2]);
        int o3 = __builtin_nontemporal_load(&eidx[e + 3]);
        acc += xt[o0 + lane] + xt[o1 + lane] + xt[o2 + lane] + xt[o3 + lane];
    }
    for (; e < start + na; e++)
        acc += xt[__builtin_nontemporal_load(&eidx[e]) + lane];
    float wsum = 0.f;
    for (int i = start + na + lane; i < end; i += 64)
        wsum += __int_as_float(__builtin_nontemporal_load(&eidx[i]));
#pragma unroll
    for (int off = 32; off > 0; off >>= 1) wsum += __shfl_down(wsum, off);
    wsum = __shfl(wsum, 0);
    float di = dinv[node];
    vL[w][lane] = di * (acc + xt[(n << 6) + lane]);
    if (lane == 0) al[w] = di * (wsum + di);
    __syncthreads();   // covers Wt/sb/st staging + all vL/al

    // ---- GEMM phase: node nl = w, output columns j=lane and j+64 ----------
    {
        float s0 = 0.f, s1 = 0.f;
        const float4* v4 = (const float4*)vL[w];
#pragma unroll
        for (int k4 = 0; k4 < 16; k4++) {
            float4 vv = v4[k4];                          // broadcast (same addr per wave)
            float4 w0 = *(const float4*)&Wt[lane][k4 * 4];
            float4 w1v = *(const float4*)&Wt[lane + 64][k4 * 4];
            s0 += vv.x * w0.x + vv.y * w0.y + vv.z * w0.z + vv.w * w0.w;
            s1 += vv.x * w1v.x + vv.y * w1v.y + vv.z * w1v.z + vv.w * w1v.w;
        }
        float a = al[w];
        part[w][lane]      = fmaxf(sb[lane] * s0 + st[lane], 0.f) * a;
        part[w][lane + 64] = fmaxf(sb[lane + 64] * s1 + st[lane + 64], 0.f) * a;
    }
    __syncthreads();
    if (tid < 128) {
        float s = 0.f;
#pragma unroll
        for (int nl = 0; nl < 16; nl++) s += part[nl][tid];
        __builtin_nontemporal_store(s, &partial[(size_t)blockIdx.x * 128 + tid]);
    }
}

// K5: fold the 10000 block partials into pooled[t][128]. 128 blocks.
__global__ __launch_bounds__(128) void k_pool_reduce(const float* __restrict__ partial,
                                                     float* __restrict__ pooled) {
    const int t = blockIdx.x >> 4;      // 0..7
    const int s = blockIdx.x & 15;      // 0..15
    const int j = threadIdx.x;
    float sum = 0.f;
    for (int c = s; c < N / 16; c += 16)
        sum += partial[(size_t)(c * 8 + t) * 128 + j];
    atomicAdd(&pooled[t * 128 + j], sum);
}

// K6a: warm every XCD's L2 with the recurrence weights (768 KB).
__global__ __launch_bounds__(256) void k_warm(const float* __restrict__ a,
                                              const float* __restrict__ b,
                                              const float* __restrict__ c,
                                              float* __restrict__ sink) {
    int slice = blockIdx.x >> 3;           // 0..7, 24576 floats each
    int start = slice * 24576;
    float s = 0.f;
    for (int i = start + threadIdx.x; i < start + 24576; i += 256) {
        float v;
        if (i < 65536) v = a[i];
        else if (i < 131072) v = b[i - 65536];
        else v = c[i - 131072];
        s += v;
    }
    sink[blockIdx.x * 256 + threadIdx.x] = s;
}

// K6b: emb = bn2(pooled/N @ W2 + b2) and layer-0 x-part gates.
__global__ __launch_bounds__(512) void k_emb(
    const float* __restrict__ pooled,
    const float* __restrict__ W2, const float* __restrict__ b2,
    const float* __restrict__ g2, const float* __restrict__ be2,
    const float* __restrict__ m2, const float* __restrict__ v2,
    const float* __restrict__ Wih0, const float* __restrict__ bih0,
    const float* __restrict__ bhh0, float* __restrict__ gx0_g) {
    const int t = blockIdx.x, tid = threadIdx.x;
    __shared__ float pm[128];
    __shared__ float es[128];
    if (tid < 128) pm[tid] = pooled[t * 128 + tid] * (1.0f / N);
    __syncthreads();
    if (tid < 128) {
        float s = g2[tid] * rsqrtf(v2[tid] + EPS);
        float sh = be2[tid] - m2[tid] * s;
        float dot = 0.f;
#pragma unroll 8
        for (int k = 0; k < 128; k++) dot += pm[k] * W2[k * 128 + tid];
        es[tid] = s * (dot + b2[tid]) + sh;
    }
    __syncthreads();
    float dot = bih0[tid] + bhh0[tid];
    const float4* w = (const float4*)(Wih0 + tid * 128);
    const float4* e4 = (const float4*)es;
#pragma unroll
    for (int k4 = 0; k4 < 32; k4++) {
        float4 a = w[k4], bb = e4[k4];
        dot += a.x * bb.x + a.y * bb.y + a.z * bb.z + a.w * bb.w;
    }
    gx0_g[t * 512 + tid] = dot;
}

// K6c: single block, 1024 threads. Thread (r = tid&511, hf = tid>>9) owns a
// HALF gate row (16 float4 = 64 VGPRs). Halves combine through LDS part[].
__global__ __launch_bounds__(1024, 4) void k_head(
    const float* __restrict__ gx0_g,
    const float* __restrict__ Whh0, const float* __restrict__ Whh1,
    const float* __restrict__ Wih1, const float* __restrict__ bih1,
    const float* __restrict__ bhh1,
    const float* __restrict__ Wc, const float* __restrict__ bc,
    float* __restrict__ out) {
    __shared__ float gx0[T][512];
    __shared__ float gx1h[2][T][512];
    __shared__ float ys[T][128];
    __shared__ float h[128];
    __shared__ float part[1024];
    const int tid = threadIdx.x;
    const int r = tid & 511, hf = tid >> 9;

    for (int i = tid; i < T * 512; i += 1024) gx0[i >> 9][i & 511] = gx0_g[i];
    if (tid < 128) h[tid] = 0.f;

    float4 w[16];
    {
        const float4* p = (const float4*)(Whh0 + r * 128 + hf * 64);
#pragma unroll
        for (int k = 0; k < 16; k++) w[k] = p[k];
    }
    float c = 0.f;
    __syncthreads();

    // LSTM layer 0
    for (int t = 0; t < T; t++) {
        const float4* h4 = ((const float4*)h) + hf * 16;
        float dot = 0.f;
#pragma unroll
        for (int k = 0; k < 16; k++) {
            float4 hv = h4[k];
            dot += w[k].x * hv.x + w[k].y * hv.y + w[k].z * hv.z + w[k].w * hv.w;
        }
        part[tid] = dot;
        __syncthreads();
        if (tid < 128) {
            float i_ = gx0[t][tid]       + part[tid]       + part[512 + tid];
            float f_ = gx0[t][128 + tid] + part[128 + tid] + part[640 + tid];
            float g_ = gx0[t][256 + tid] + part[256 + tid] + part[768 + tid];
            float o_ = gx0[t][384 + tid] + part[384 + tid] + part[896 + tid];
            c = sigm(f_) * c + sigm(i_) * tanhf(g_);
            float hv = sigm(o_) * tanhf(c);
            h[tid] = hv;
            ys[t][tid] = hv;
        }
        __syncthreads();
    }

    // gx1 halves
    {
        const float4* p = (const float4*)(Wih1 + r * 128 + hf * 64);
#pragma unroll
        for (int k = 0; k < 16; k++) w[k] = p[k];
        float bias = (hf == 0) ? (bih1[r] + bhh1[r]) : 0.f;
        for (int t = 0; t < T; t++) {
            const float4* y4 = ((const float4*)ys[t]) + hf * 16;
            float dot = bias;
#pragma unroll
            for (int k = 0; k < 16; k++) {
                float4 yv = y4[k];
                dot += w[k].x * yv.x + w[k].y * yv.y + w[k].z * yv.z + w[k].w * yv.w;
            }
            gx1h[hf][t][r] = dot;
        }
    }

    // LSTM layer 1
    {
        const float4* p = (const float4*)(Whh1 + r * 128 + hf * 64);
#pragma unroll
        for (int k = 0; k < 16; k++) w[k] = p[k];
    }
    if (tid < 128) h[tid] = 0.f;
    c = 0.f;
    __syncthreads();
    for (int t = 0; t < T; t++) {
        const float4* h4 = ((const float4*)h) + hf * 16;
        float dot = 0.f;
#pragma unroll
        for (int k = 0; k < 16; k++) {
            float4 hv = h4[k];
            dot += w[k].x * hv.x + w[k].y * hv.y + w[k].z * hv.z + w[k].w * hv.w;
        }
        part[tid] = dot;
        __syncthreads();
        if (tid < 128) {
            float i_ = gx1h[0][t][tid]       + gx1h[1][t][tid]       + part[tid]       + part[512 + tid];
            float f_ = gx1h[0][t][128 + tid] + gx1h[1][t][128 + tid] + part[128 + tid] + part[640 + tid];
            float g_ = gx1h[0][t][256 + tid] + gx1h[1][t][256 + tid] + part[256 + tid] + part[768 + tid];
            float o_ = gx1h[0][t][384 + tid] + gx1h[1][t][384 + tid] + part[384 + tid] + part[896 + tid];
            c = sigm(f_) * c + sigm(i_) * tanhf(g_);
            h[tid] = sigm(o_) * tanhf(c);
        }
        __syncthreads();
    }

    if (tid < 2) {
        float dot = bc[tid];
#pragma unroll 8
        for (int k = 0; k < 128; k++) dot += h[k] * Wc[tid * 128 + k];
        out[tid] = dot;
    }
    if (tid < 128) out[2 + tid] = h[tid];
}

// ---------------------------------------------------------------------------
extern "C" void kernel_launch(void* const* d_in, const int* in_sizes, int n_in,
                              void* d_out, int out_size, void* d_ws, size_t ws_size,
                              hipStream_t stream) {
    float*       x    = (float*)d_in[0];          // scaled in-place by k_scale
    const int*   edges= (const int*)d_in[1];
    const float* W1   = (const float*)d_in[2];
    const float* b1   = (const float*)d_in[3];
    const float* g1   = (const float*)d_in[4];
    const float* be1  = (const float*)d_in[5];
    const float* m1   = (const float*)d_in[6];
    const float* v1   = (const float*)d_in[7];
    const float* W2   = (const float*)d_in[8];
    const float* b2   = (const float*)d_in[9];
    const float* g2   = (const float*)d_in[10];
    const float* be2  = (const float*)d_in[11];
    const float* m2   = (const float*)d_in[12];
    const float* v2   = (const float*)d_in[13];
    const float* Wih0 = (const float*)d_in[14];
    const float* Whh0 = (const float*)d_in[15];
    const float* bih0 = (const float*)d_in[16];
    const float* bhh0 = (const float*)d_in[17];
    const float* Wih1 = (const float*)d_in[18];
    const float* Whh1 = (const float*)d_in[19];
    const float* bih1 = (const float*)d_in[20];
    const float* bhh1 = (const float*)d_in[21];
    const float* Wc   = (const float*)d_in[22];
    const float* bc   = (const float*)d_in[23];

    char* base = (char*)d_ws;
    // Aliasing: hist_g (10.24 MB) dead after k_base; base_g (20.48 MB) dead
    // after k_fill; partial (5.12 MB) written in k_gather_gemm (after k_fill)
    // — all three share the first 31 MB region safely.
    unsigned int* hist_g  = (unsigned int*)base;                      // T*NB*NPACK u32
    unsigned int* base_g  = (unsigned int*)(base + (size_t)T * NB * NPACK * 4);
    float*        partial = (float*)base;                             // 10000*128 f32
    char* p = base + (size_t)T * NB * NPACK * 4 + (size_t)T * NB * N * 4;
    int*   offs  = (int*)p;                 p += (size_t)(T * N + 1) * 4 + 12; // keep 16B align
    int*   dega  = (int*)p;                 p += (size_t)T * N * 4;
    float* dinv  = (float*)p;               p += (size_t)T * N * 4;
    int*   tot   = (int*)p;                 p += (size_t)T * N * 4;   // reused as warm sink
    int*   eidx  = (int*)p;                 p += (size_t)T * 2 * E * 4;
    float* pooled= (float*)p;               p += (size_t)T * 128 * 4;
    float* gx0_g = (float*)p;

    (void)hipMemsetAsync(pooled, 0, T * 128 * sizeof(float), stream);

    dim3 gs(T, NB);
    k_hist<<<gs, 1024, 0, stream>>>(edges, hist_g);
    k_colsum<<<(T * NPACK + 255) / 256, 256, 0, stream>>>(hist_g, tot, dega, dinv);
    k_scanN<<<T, 1024, 0, stream>>>(tot, offs);
    k_base<<<(T * N + 255) / 256, 256, 0, stream>>>(hist_g, offs, base_g);
    k_scale<<<(T * N * 16 + 255) / 256, 256, 0, stream>>>(x, dinv);
    k_fill<<<gs, 1024, 0, stream>>>(edges, base_g, dinv, eidx);
    k_gather_gemm<<<(T * N) / 16, 1024, 0, stream>>>(eidx, offs, dega, dinv, x,
                                                     W1, b1, g1, be1, m1, v1, partial);
    k_pool_reduce<<<128, 128, 0, stream>>>(partial, pooled);

    k_warm<<<64, 256, 0, stream>>>(Whh0, Whh1, Wih1, (float*)tot);
    k_emb<<<T, 512, 0, stream>>>(pooled, W2, b2, g2, be2, m2, v2, Wih0, bih0, bhh0, gx0_g);
    k_head<<<1, 1024, 0, stream>>>(gx0_g, Whh0, Whh1, Wih1, bih1, bhh1, Wc, bc, (float*)d_out);
}

// Round 12
// 550.383 us; speedup vs baseline: 1.0341x; 1.0341x over previous
//
#include <hip/hip_runtime.h>
#include <hip/hip_fp16.h>
#include <math.h>

#define T 8
#define N 20000
#define E 320000
#define EPS 1e-5f
#define NB 32          // item-sort blocks per t: 16 agg-half + 16 w-half
#define CHUNK 20000    // E/16 items per block
#define NPACK 10000    // N/2 packed u32 (2 x u16 counters)

__device__ __forceinline__ float sigm(float x) { return 1.0f / (1.0f + expf(-x)); }

// ---------------------------------------------------------------------------
// K1: per-(t,block) LDS histogram of item keys. Blocks 0..15 histogram dst
// over agg items; blocks 16..31 histogram src over w items.
__global__ __launch_bounds__(1024) void k_hist(const int* __restrict__ edges,
                                               unsigned int* __restrict__ hist_g) {
    __shared__ unsigned int h32[NPACK];
    const int t = blockIdx.x, b = blockIdx.y;
    const int tid = threadIdx.x;
    for (int i = tid; i < NPACK; i += 1024) h32[i] = 0;
    __syncthreads();
    const bool isAgg = (b < 16);
    const int cs = (isAgg ? b : b - 16) * CHUNK;
    const int* keys = edges + (size_t)t * 2 * E + (isAgg ? E : 0) + cs;
    for (int i = tid; i < CHUNK; i += 1024) {
        int k = keys[i];
        atomicAdd(&h32[k >> 1], 1u << ((k & 1) * 16));
    }
    __syncthreads();
    unsigned int* out = hist_g + (size_t)(t * NB + b) * NPACK;
    for (int i = tid; i < NPACK; i += 1024) out[i] = h32[i];
}

// K2a: column sum over the 32 blocks — one thread per packed key pair.
__global__ __launch_bounds__(256) void k_colsum(
    const unsigned int* __restrict__ hist_g, int* __restrict__ tot,
    int* __restrict__ dega, float* __restrict__ dinv) {
    int idx = blockIdx.x * 256 + threadIdx.x;
    if (idx >= T * NPACK) return;
    int t = idx / NPACK, i = idx - t * NPACK;
    const unsigned int* hp = hist_g + (size_t)t * NB * NPACK + i;
    unsigned int a0 = 0, a1 = 0, w0 = 0, w1 = 0;
#pragma unroll
    for (int b = 0; b < 16; b++) {
        unsigned int h = hp[(size_t)b * NPACK];
        a0 += h & 0xffffu; a1 += h >> 16;
    }
#pragma unroll
    for (int b = 16; b < 32; b++) {
        unsigned int h = hp[(size_t)b * NPACK];
        w0 += h & 0xffffu; w1 += h >> 16;
    }
    int n0 = t * N + 2 * i;
    tot[n0]     = (int)(a0 + w0);
    tot[n0 + 1] = (int)(a1 + w1);
    dega[n0]     = (int)a0;
    dega[n0 + 1] = (int)a1;
    dinv[n0]     = rsqrtf((float)a0 + 1.0f);
    dinv[n0 + 1] = rsqrtf((float)a1 + 1.0f);
}

// K2b: per-t exclusive prefix over 20000 node totals -> offs (+ sentinel).
__global__ __launch_bounds__(1024) void k_scanN(const int* __restrict__ tot,
                                                int* __restrict__ offs) {
    const int t = blockIdx.x, tid = threadIdx.x;
    __shared__ int sh[1024];
    int local[20];
    int sum = 0;
    if (tid < 1000) {
        const int* tp = tot + t * N + tid * 20;
#pragma unroll
        for (int i = 0; i < 20; i++) { local[i] = tp[i]; sum += local[i]; }
    }
    sh[tid] = sum;
    __syncthreads();
    for (int off = 1; off < 1024; off <<= 1) {
        int v = (tid >= off) ? sh[tid - off] : 0;
        __syncthreads();
        sh[tid] += v;
        __syncthreads();
    }
    if (tid < 1000) {
        int run = t * 2 * E + sh[tid] - sum;
        int* op = offs + t * N + tid * 20;
#pragma unroll
        for (int i = 0; i < 20; i++) { op[i] = run; run += local[i]; }
    }
    if (t == T - 1 && tid == 0) offs[T * N] = 2 * T * E;
}

// K2c: per-node running prefix over the 32 blocks -> base_g.
__global__ __launch_bounds__(256) void k_base(
    const unsigned int* __restrict__ hist_g, const int* __restrict__ offs,
    unsigned int* __restrict__ base_g) {
    int node = blockIdx.x * 256 + threadIdx.x;
    if (node >= T * N) return;
    int t = node / N, n = node - t * N;
    const unsigned short* h16 = (const unsigned short*)hist_g;
    int run = offs[node];
#pragma unroll
    for (int b = 0; b < NB; b++) {
        size_t o = (size_t)(t * NB + b) * N + n;
        base_g[o] = (unsigned int)run;
        run += h16[o];
    }
}

// K2d: xh[t][n][k] = half(dinv[t][n] * x[t][n][k]). 20.5 MB total;
// per-t slice 2.56 MB -> fully resident in one XCD's 4 MiB L2.
__global__ __launch_bounds__(256) void k_cvt(const float* __restrict__ x,
                                             const float* __restrict__ dinv,
                                             __half* __restrict__ xh) {
    int idx = blockIdx.x * 256 + threadIdx.x;   // one float4 per thread
    if (idx >= T * N * 16) return;
    float d = dinv[idx >> 4];
    float4 vv = ((const float4*)x)[idx];
    __half h0 = __float2half(vv.x * d);
    __half h1 = __float2half(vv.y * d);
    __half h2 = __float2half(vv.z * d);
    __half h3 = __float2half(vv.w * d);
    ushort4 pack;
    pack.x = *(unsigned short*)&h0;
    pack.y = *(unsigned short*)&h1;
    pack.z = *(unsigned short*)&h2;
    pack.w = *(unsigned short*)&h3;
    ((ushort4*)xh)[idx] = pack;
}

// K3: fill. Position = global per-(block,key) base + LDS u16 running count.
// One 4B scattered write per item:
//   agg item -> eidx = src*64 (row element offset)
//   w   item -> eidx = float bits of dinv[dst]
__global__ __launch_bounds__(1024) void k_fill(const int* __restrict__ edges,
                                               const unsigned int* __restrict__ base_g,
                                               const float* __restrict__ dinv,
                                               int* __restrict__ eidx) {
    __shared__ unsigned int c32[NPACK];
    const int t = blockIdx.x, b = blockIdx.y;
    const int tid = threadIdx.x;
    for (int i = tid; i < NPACK; i += 1024) c32[i] = 0;
    __syncthreads();
    const bool isAgg = (b < 16);
    const int cs = (isAgg ? b : b - 16) * CHUNK;
    const int* keys = edges + (size_t)t * 2 * E + (isAgg ? E : 0) + cs;
    const int* pays = edges + (size_t)t * 2 * E + (isAgg ? 0 : E) + cs;
    const unsigned int* base = base_g + (size_t)(t * NB + b) * N;
    const float* dv = dinv + t * N;
    if (isAgg) {
        for (int i = tid; i < CHUNK; i += 1024) {
            int k = keys[i];
            int p = pays[i];
            unsigned int sh = (unsigned int)((k & 1) * 16);
            unsigned int old = atomicAdd(&c32[k >> 1], 1u << sh);
            unsigned int cnt = (old >> sh) & 0xffffu;
            eidx[base[k] + cnt] = p << 6;
        }
    } else {
        for (int i = tid; i < CHUNK; i += 1024) {
            int k = keys[i];
            int p = pays[i];
            unsigned int sh = (unsigned int)((k & 1) * 16);
            unsigned int old = atomicAdd(&c32[k >> 1], 1u << sh);
            unsigned int cnt = (old >> sh) & 0xffffu;
            eidx[base[k] + cnt] = __float_as_int(dv[p]);
        }
    }
}

// K4: gather — one wave per node, lane = feature. fp16 rows (128 B each,
// L2-resident slice), 4 independent loads in flight (R8 structure).
// t = blockIdx&7 keeps each XCD on one t's xh-slice.
__global__ __launch_bounds__(256) void k_gather(
    const int* __restrict__ eidx, const int* __restrict__ offs,
    const int* __restrict__ dega, const float* __restrict__ dinv,
    const __half* __restrict__ xh, float* __restrict__ v, float* __restrict__ alpha) {
    const int t = blockIdx.x & 7;
    const int n = ((blockIdx.x >> 3) << 2) + (threadIdx.x >> 6);
    const int lane = threadIdx.x & 63;
    if (n >= N) return;
    const int node = t * N + n;
    int start = offs[node];
    int end = offs[node + 1];
    int na = dega[node];
    const __half* xt = xh + (size_t)t * N * 64;
    float acc = 0.f;
    int e = start, stop4 = start + (na & ~3);
    for (; e < stop4; e += 4) {
        int o0 = __builtin_nontemporal_load(&eidx[e + 0]);
        int o1 = __builtin_nontemporal_load(&eidx[e + 1]);
        int o2 = __builtin_nontemporal_load(&eidx[e + 2]);
        int o3 = __builtin_nontemporal_load(&eidx[e + 3]);
        float x0 = __half2float(xt[o0 + lane]);
        float x1 = __half2float(xt[o1 + lane]);
        float x2 = __half2float(xt[o2 + lane]);
        float x3 = __half2float(xt[o3 + lane]);
        acc += x0 + x1 + x2 + x3;
    }
    for (; e < start + na; e++)
        acc += __half2float(xt[__builtin_nontemporal_load(&eidx[e]) + lane]);
    float wsum = 0.f;
    for (int i = start + na + lane; i < end; i += 64)
        wsum += __int_as_float(__builtin_nontemporal_load(&eidx[i]));
#pragma unroll
    for (int off = 32; off > 0; off >>= 1) wsum += __shfl_down(wsum, off);
    wsum = __shfl(wsum, 0);
    float di = dinv[node];
    v[(size_t)node * 64 + lane] = di * (acc + __half2float(xt[(n << 6) + lane]));
    if (lane == 0) alpha[node] = di * (wsum + di);
}

// K5: per-node layer-1 GEMM (64->128), BN1 + ReLU, alpha-weighted pool.
__global__ __launch_bounds__(256) void k_gemm_pool(
    const float* __restrict__ v, const float* __restrict__ alpha,
    const float* __restrict__ W1, const float* __restrict__ b1,
    const float* __restrict__ g1, const float* __restrict__ be1,
    const float* __restrict__ m1, const float* __restrict__ v1,
    float* __restrict__ pooled) {
    __shared__ float Ws[64 * 128];          // [k][j]
    __shared__ float sb[128], st[128], pool[128];
    const int t = blockIdx.y;
    const int tid = threadIdx.x;
    const int n = blockIdx.x * 256 + tid;

    for (int i = tid; i < 64 * 128; i += 256) Ws[i] = W1[i];
    if (tid < 128) {
        float s = g1[tid] * rsqrtf(v1[tid] + EPS);
        sb[tid] = s;
        st[tid] = s * b1[tid] + be1[tid] - m1[tid] * s;
        pool[tid] = 0.0f;
    }
    __syncthreads();

    float vv[64];
    float al = 0.0f;
    if (n < N) {
        int node = t * N + n;
        al = alpha[node];
        const float4* v4 = (const float4*)(v + (size_t)node * 64);
#pragma unroll
        for (int k4 = 0; k4 < 16; k4++) {
            float4 a = v4[k4];
            vv[4 * k4 + 0] = a.x; vv[4 * k4 + 1] = a.y;
            vv[4 * k4 + 2] = a.z; vv[4 * k4 + 3] = a.w;
        }
    } else {
#pragma unroll
        for (int k = 0; k < 64; k++) vv[k] = 0.0f;
    }

    const int lane = tid & 63;
    for (int j4 = 0; j4 < 32; j4++) {
        float s0 = 0.f, s1 = 0.f, s2 = 0.f, s3 = 0.f;
#pragma unroll
        for (int k = 0; k < 64; k++) {
            float4 wv = *(const float4*)&Ws[k * 128 + j4 * 4];
            s0 += vv[k] * wv.x;
            s1 += vv[k] * wv.y;
            s2 += vv[k] * wv.z;
            s3 += vv[k] * wv.w;
        }
        int j = j4 * 4;
        float y0 = fmaxf(sb[j + 0] * s0 + st[j + 0], 0.f) * al;
        float y1 = fmaxf(sb[j + 1] * s1 + st[j + 1], 0.f) * al;
        float y2 = fmaxf(sb[j + 2] * s2 + st[j + 2], 0.f) * al;
        float y3 = fmaxf(sb[j + 3] * s3 + st[j + 3], 0.f) * al;
#pragma unroll
        for (int off = 32; off > 0; off >>= 1) {
            y0 += __shfl_down(y0, off);
            y1 += __shfl_down(y1, off);
            y2 += __shfl_down(y2, off);
            y3 += __shfl_down(y3, off);
        }
        if (lane == 0) {
            atomicAdd(&pool[j + 0], y0);
            atomicAdd(&pool[j + 1], y1);
            atomicAdd(&pool[j + 2], y2);
            atomicAdd(&pool[j + 3], y3);
        }
    }
    __syncthreads();
    if (tid < 128) atomicAdd(&pooled[t * 128 + tid], pool[tid]);
}

// K6a: warm every XCD's L2 with the recurrence weights (768 KB).
__global__ __launch_bounds__(256) void k_warm(const float* __restrict__ a,
                                              const float* __restrict__ b,
                                              const float* __restrict__ c,
                                              float* __restrict__ sink) {
    int slice = blockIdx.x >> 3;           // 0..7, 24576 floats each
    int start = slice * 24576;
    float s = 0.f;
    for (int i = start + threadIdx.x; i < start + 24576; i += 256) {
        float v;
        if (i < 65536) v = a[i];
        else if (i < 131072) v = b[i - 65536];
        else v = c[i - 131072];
        s += v;
    }
    sink[blockIdx.x * 256 + threadIdx.x] = s;
}

// K6b: emb = bn2(pooled/N @ W2 + b2) and layer-0 x-part gates.
__global__ __launch_bounds__(512) void k_emb(
    const float* __restrict__ pooled,
    const float* __restrict__ W2, const float* __restrict__ b2,
    const float* __restrict__ g2, const float* __restrict__ be2,
    const float* __restrict__ m2, const float* __restrict__ v2,
    const float* __restrict__ Wih0, const float* __restrict__ bih0,
    const float* __restrict__ bhh0, float* __restrict__ gx0_g) {
    const int t = blockIdx.x, tid = threadIdx.x;
    __shared__ float pm[128];
    __shared__ float es[128];
    if (tid < 128) pm[tid] = pooled[t * 128 + tid] * (1.0f / N);
    __syncthreads();
    if (tid < 128) {
        float s = g2[tid] * rsqrtf(v2[tid] + EPS);
        float sh = be2[tid] - m2[tid] * s;
        float dot = 0.f;
#pragma unroll 8
        for (int k = 0; k < 128; k++) dot += pm[k] * W2[k * 128 + tid];
        es[tid] = s * (dot + b2[tid]) + sh;
    }
    __syncthreads();
    float dot = bih0[tid] + bhh0[tid];
    const float4* w = (const float4*)(Wih0 + tid * 128);
    const float4* e4 = (const float4*)es;
#pragma unroll
    for (int k4 = 0; k4 < 32; k4++) {
        float4 a = w[k4], bb = e4[k4];
        dot += a.x * bb.x + a.y * bb.y + a.z * bb.z + a.w * bb.w;
    }
    gx0_g[t * 512 + tid] = dot;
}

// K6c: single block, 1024 threads. Thread (r = tid&511, hf = tid>>9) owns a
// HALF gate row (16 float4 = 64 VGPRs). Halves combine through LDS part[].
__global__ __launch_bounds__(1024, 4) void k_head(
    const float* __restrict__ gx0_g,
    const float* __restrict__ Whh0, const float* __restrict__ Whh1,
    const float* __restrict__ Wih1, const float* __restrict__ bih1,
    const float* __restrict__ bhh1,
    const float* __restrict__ Wc, const float* __restrict__ bc,
    float* __restrict__ out) {
    __shared__ float gx0[T][512];
    __shared__ float gx1h[2][T][512];
    __shared__ float ys[T][128];
    __shared__ float h[128];
    __shared__ float part[1024];
    const int tid = threadIdx.x;
    const int r = tid & 511, hf = tid >> 9;

    for (int i = tid; i < T * 512; i += 1024) gx0[i >> 9][i & 511] = gx0_g[i];
    if (tid < 128) h[tid] = 0.f;

    float4 w[16];
    {
        const float4* p = (const float4*)(Whh0 + r * 128 + hf * 64);
#pragma unroll
        for (int k = 0; k < 16; k++) w[k] = p[k];
    }
    float c = 0.f;
    __syncthreads();

    // LSTM layer 0
    for (int t = 0; t < T; t++) {
        const float4* h4 = ((const float4*)h) + hf * 16;
        float dot = 0.f;
#pragma unroll
        for (int k = 0; k < 16; k++) {
            float4 hv = h4[k];
            dot += w[k].x * hv.x + w[k].y * hv.y + w[k].z * hv.z + w[k].w * hv.w;
        }
        part[tid] = dot;
        __syncthreads();
        if (tid < 128) {
            float i_ = gx0[t][tid]       + part[tid]       + part[512 + tid];
            float f_ = gx0[t][128 + tid] + part[128 + tid] + part[640 + tid];
            float g_ = gx0[t][256 + tid] + part[256 + tid] + part[768 + tid];
            float o_ = gx0[t][384 + tid] + part[384 + tid] + part[896 + tid];
            c = sigm(f_) * c + sigm(i_) * tanhf(g_);
            float hv = sigm(o_) * tanhf(c);
            h[tid] = hv;
            ys[t][tid] = hv;
        }
        __syncthreads();
    }

    // gx1 halves
    {
        const float4* p = (const float4*)(Wih1 + r * 128 + hf * 64);
#pragma unroll
        for (int k = 0; k < 16; k++) w[k] = p[k];
        float bias = (hf == 0) ? (bih1[r] + bhh1[r]) : 0.f;
        for (int t = 0; t < T; t++) {
            const float4* y4 = ((const float4*)ys[t]) + hf * 16;
            float dot = bias;
#pragma unroll
            for (int k = 0; k < 16; k++) {
                float4 yv = y4[k];
                dot += w[k].x * yv.x + w[k].y * yv.y + w[k].z * yv.z + w[k].w * yv.w;
            }
            gx1h[hf][t][r] = dot;
        }
    }

    // LSTM layer 1
    {
        const float4* p = (const float4*)(Whh1 + r * 128 + hf * 64);
#pragma unroll
        for (int k = 0; k < 16; k++) w[k] = p[k];
    }
    if (tid < 128) h[tid] = 0.f;
    c = 0.f;
    __syncthreads();
    for (int t = 0; t < T; t++) {
        const float4* h4 = ((const float4*)h) + hf * 16;
        float dot = 0.f;
#pragma unroll
        for (int k = 0; k < 16; k++) {
            float4 hv = h4[k];
            dot += w[k].x * hv.x + w[k].y * hv.y + w[k].z * hv.z + w[k].w * hv.w;
        }
        part[tid] = dot;
        __syncthreads();
        if (tid < 128) {
            float i_ = gx1h[0][t][tid]       + gx1h[1][t][tid]       + part[tid]       + part[512 + tid];
            float f_ = gx1h[0][t][128 + tid] + gx1h[1][t][128 + tid] + part[128 + tid] + part[640 + tid];
            float g_ = gx1h[0][t][256 + tid] + gx1h[1][t][256 + tid] + part[256 + tid] + part[768 + tid];
            float o_ = gx1h[0][t][384 + tid] + gx1h[1][t][384 + tid] + part[384 + tid] + part[896 + tid];
            c = sigm(f_) * c + sigm(i_) * tanhf(g_);
            h[tid] = sigm(o_) * tanhf(c);
        }
        __syncthreads();
    }

    if (tid < 2) {
        float dot = bc[tid];
#pragma unroll 8
        for (int k = 0; k < 128; k++) dot += h[k] * Wc[tid * 128 + k];
        out[tid] = dot;
    }
    if (tid < 128) out[2 + tid] = h[tid];
}

// ---------------------------------------------------------------------------
extern "C" void kernel_launch(void* const* d_in, const int* in_sizes, int n_in,
                              void* d_out, int out_size, void* d_ws, size_t ws_size,
                              hipStream_t stream) {
    const float* x    = (const float*)d_in[0];
    const int*   edges= (const int*)d_in[1];
    const float* W1   = (const float*)d_in[2];
    const float* b1   = (const float*)d_in[3];
    const float* g1   = (const float*)d_in[4];
    const float* be1  = (const float*)d_in[5];
    const float* m1   = (const float*)d_in[6];
    const float* v1   = (const float*)d_in[7];
    const float* W2   = (const float*)d_in[8];
    const float* b2   = (const float*)d_in[9];
    const float* g2   = (const float*)d_in[10];
    const float* be2  = (const float*)d_in[11];
    const float* m2   = (const float*)d_in[12];
    const float* v2   = (const float*)d_in[13];
    const float* Wih0 = (const float*)d_in[14];
    const float* Whh0 = (const float*)d_in[15];
    const float* bih0 = (const float*)d_in[16];
    const float* bhh0 = (const float*)d_in[17];
    const float* Wih1 = (const float*)d_in[18];
    const float* Whh1 = (const float*)d_in[19];
    const float* bih1 = (const float*)d_in[20];
    const float* bhh1 = (const float*)d_in[21];
    const float* Wc   = (const float*)d_in[22];
    const float* bc   = (const float*)d_in[23];

    char* base = (char*)d_ws;
    // v (41 MB) aliases hist_g (10.24 MB) + base_g (20.48 MB): hist dead after
    // k_base, base_g dead after k_fill, v written in k_gather — safe ordering.
    float*        v      = (float*)base;                              // T*N*64 f32
    unsigned int* hist_g = (unsigned int*)base;                       // T*NB*NPACK u32
    unsigned int* base_g = (unsigned int*)(base + (size_t)T * NB * NPACK * 4);
    char* p = base + (size_t)T * N * 64 * 4;
    __half* xh   = (__half*)p;              p += (size_t)T * N * 64 * 2;  // 20.5 MB
    int*   offs  = (int*)p;                 p += (size_t)(T * N + 1) * 4 + 12; // keep 16B align
    int*   dega  = (int*)p;                 p += (size_t)T * N * 4;
    float* dinv  = (float*)p;               p += (size_t)T * N * 4;
    float* alpha = (float*)p;               p += (size_t)T * N * 4;
    int*   tot   = (int*)p;                 p += (size_t)T * N * 4;   // reused as warm sink
    int*   eidx  = (int*)p;                 p += (size_t)T * 2 * E * 4;
    float* pooled= (float*)p;               p += (size_t)T * 128 * 4;
    float* gx0_g = (float*)p;

    (void)hipMemsetAsync(pooled, 0, T * 128 * sizeof(float), stream);

    dim3 gs(T, NB);
    k_hist<<<gs, 1024, 0, stream>>>(edges, hist_g);
    k_colsum<<<(T * NPACK + 255) / 256, 256, 0, stream>>>(hist_g, tot, dega, dinv);
    k_scanN<<<T, 1024, 0, stream>>>(tot, offs);
    k_base<<<(T * N + 255) / 256, 256, 0, stream>>>(hist_g, offs, base_g);
    k_cvt<<<(T * N * 16 + 255) / 256, 256, 0, stream>>>(x, dinv, xh);
    k_fill<<<gs, 1024, 0, stream>>>(edges, base_g, dinv, eidx);
    k_gather<<<(T * N) / 4, 256, 0, stream>>>(eidx, offs, dega, dinv, xh, v, alpha);

    dim3 g4((N + 255) / 256, T);
    k_gemm_pool<<<g4, 256, 0, stream>>>(v, alpha, W1, b1, g1, be1, m1, v1, pooled);

    k_warm<<<64, 256, 0, stream>>>(Whh0, Whh1, Wih1, (float*)tot);
    k_emb<<<T, 512, 0, stream>>>(pooled, W2, b2, g2, be2, m2, v2, Wih0, bih0, bhh0, gx0_g);
    k_head<<<1, 1024, 0, stream>>>(gx0_g, Whh0, Whh1, Wih1, bih1, bhh1, Wc, bc, (float*)d_out);
}

// Round 13
// 500.690 us; speedup vs baseline: 1.1367x; 1.0992x over previous
//
#include <hip/hip_runtime.h>
#include <hip/hip_fp16.h>
#include <math.h>

#define T 8
#define N 20000
#define E 320000
#define EPS 1e-5f
#define NB 32          // item-sort blocks per t: 16 agg-half + 16 w-half
#define CHUNK 20000    // E/16 items per block
#define NPACK 10000    // N/2 packed u32 (2 x u16 counters)

__device__ __forceinline__ float sigm(float x) { return 1.0f / (1.0f + expf(-x)); }

// ---------------------------------------------------------------------------
// K1: per-(t,block) LDS histogram of item keys. Blocks 0..15 histogram dst
// over agg items; blocks 16..31 histogram src over w items.
__global__ __launch_bounds__(1024) void k_hist(const int* __restrict__ edges,
                                               unsigned int* __restrict__ hist_g) {
    __shared__ unsigned int h32[NPACK];
    const int t = blockIdx.x, b = blockIdx.y;
    const int tid = threadIdx.x;
    for (int i = tid; i < NPACK; i += 1024) h32[i] = 0;
    __syncthreads();
    const bool isAgg = (b < 16);
    const int cs = (isAgg ? b : b - 16) * CHUNK;
    const int* keys = edges + (size_t)t * 2 * E + (isAgg ? E : 0) + cs;
    for (int i = tid; i < CHUNK; i += 1024) {
        int k = keys[i];
        atomicAdd(&h32[k >> 1], 1u << ((k & 1) * 16));
    }
    __syncthreads();
    unsigned int* out = hist_g + (size_t)(t * NB + b) * NPACK;
    for (int i = tid; i < NPACK; i += 1024) out[i] = h32[i];
}

// K2a: column sum over the 32 blocks — one thread per packed key pair.
__global__ __launch_bounds__(256) void k_colsum(
    const unsigned int* __restrict__ hist_g, int* __restrict__ tot,
    int* __restrict__ dega, float* __restrict__ dinv) {
    int idx = blockIdx.x * 256 + threadIdx.x;
    if (idx >= T * NPACK) return;
    int t = idx / NPACK, i = idx - t * NPACK;
    const unsigned int* hp = hist_g + (size_t)t * NB * NPACK + i;
    unsigned int a0 = 0, a1 = 0, w0 = 0, w1 = 0;
#pragma unroll
    for (int b = 0; b < 16; b++) {
        unsigned int h = hp[(size_t)b * NPACK];
        a0 += h & 0xffffu; a1 += h >> 16;
    }
#pragma unroll
    for (int b = 16; b < 32; b++) {
        unsigned int h = hp[(size_t)b * NPACK];
        w0 += h & 0xffffu; w1 += h >> 16;
    }
    int n0 = t * N + 2 * i;
    tot[n0]     = (int)(a0 + w0);
    tot[n0 + 1] = (int)(a1 + w1);
    dega[n0]     = (int)a0;
    dega[n0 + 1] = (int)a1;
    dinv[n0]     = rsqrtf((float)a0 + 1.0f);
    dinv[n0 + 1] = rsqrtf((float)a1 + 1.0f);
}

// K2b: per-t exclusive prefix over 20000 node totals -> offs (+ sentinel).
__global__ __launch_bounds__(1024) void k_scanN(const int* __restrict__ tot,
                                                int* __restrict__ offs) {
    const int t = blockIdx.x, tid = threadIdx.x;
    __shared__ int sh[1024];
    int local[20];
    int sum = 0;
    if (tid < 1000) {
        const int* tp = tot + t * N + tid * 20;
#pragma unroll
        for (int i = 0; i < 20; i++) { local[i] = tp[i]; sum += local[i]; }
    }
    sh[tid] = sum;
    __syncthreads();
    for (int off = 1; off < 1024; off <<= 1) {
        int v = (tid >= off) ? sh[tid - off] : 0;
        __syncthreads();
        sh[tid] += v;
        __syncthreads();
    }
    if (tid < 1000) {
        int run = t * 2 * E + sh[tid] - sum;
        int* op = offs + t * N + tid * 20;
#pragma unroll
        for (int i = 0; i < 20; i++) { op[i] = run; run += local[i]; }
    }
    if (t == T - 1 && tid == 0) offs[T * N] = 2 * T * E;
}

// K2c: per-node running prefix over the 32 blocks -> base_g.
__global__ __launch_bounds__(256) void k_base(
    const unsigned int* __restrict__ hist_g, const int* __restrict__ offs,
    unsigned int* __restrict__ base_g) {
    int node = blockIdx.x * 256 + threadIdx.x;
    if (node >= T * N) return;
    int t = node / N, n = node - t * N;
    const unsigned short* h16 = (const unsigned short*)hist_g;
    int run = offs[node];
#pragma unroll
    for (int b = 0; b < NB; b++) {
        size_t o = (size_t)(t * NB + b) * N + n;
        base_g[o] = (unsigned int)run;
        run += h16[o];
    }
}

// K2d: xh[t][n][k] = half(dinv[t][n] * x[t][n][k]). 20.5 MB total;
// per-t slice 2.56 MB -> fully resident in one XCD's 4 MiB L2.
__global__ __launch_bounds__(256) void k_cvt(const float* __restrict__ x,
                                             const float* __restrict__ dinv,
                                             __half* __restrict__ xh) {
    int idx = blockIdx.x * 256 + threadIdx.x;   // one float4 per thread
    if (idx >= T * N * 16) return;
    float d = dinv[idx >> 4];
    float4 vv = ((const float4*)x)[idx];
    __half h0 = __float2half(vv.x * d);
    __half h1 = __float2half(vv.y * d);
    __half h2 = __float2half(vv.z * d);
    __half h3 = __float2half(vv.w * d);
    ushort4 pack;
    pack.x = *(unsigned short*)&h0;
    pack.y = *(unsigned short*)&h1;
    pack.z = *(unsigned short*)&h2;
    pack.w = *(unsigned short*)&h3;
    ((ushort4*)xh)[idx] = pack;
}

// K3: fill. Position = global per-(block,key) base + LDS u16 running count.
// One 4B scattered write per item:
//   agg item -> eidx = src*64 (row element offset)
//   w   item -> eidx = float bits of dinv[dst]
__global__ __launch_bounds__(1024) void k_fill(const int* __restrict__ edges,
                                               const unsigned int* __restrict__ base_g,
                                               const float* __restrict__ dinv,
                                               int* __restrict__ eidx) {
    __shared__ unsigned int c32[NPACK];
    const int t = blockIdx.x, b = blockIdx.y;
    const int tid = threadIdx.x;
    for (int i = tid; i < NPACK; i += 1024) c32[i] = 0;
    __syncthreads();
    const bool isAgg = (b < 16);
    const int cs = (isAgg ? b : b - 16) * CHUNK;
    const int* keys = edges + (size_t)t * 2 * E + (isAgg ? E : 0) + cs;
    const int* pays = edges + (size_t)t * 2 * E + (isAgg ? 0 : E) + cs;
    const unsigned int* base = base_g + (size_t)(t * NB + b) * N;
    const float* dv = dinv + t * N;
    if (isAgg) {
        for (int i = tid; i < CHUNK; i += 1024) {
            int k = keys[i];
            int p = pays[i];
            unsigned int sh = (unsigned int)((k & 1) * 16);
            unsigned int old = atomicAdd(&c32[k >> 1], 1u << sh);
            unsigned int cnt = (old >> sh) & 0xffffu;
            eidx[base[k] + cnt] = p << 6;
        }
    } else {
        for (int i = tid; i < CHUNK; i += 1024) {
            int k = keys[i];
            int p = pays[i];
            unsigned int sh = (unsigned int)((k & 1) * 16);
            unsigned int old = atomicAdd(&c32[k >> 1], 1u << sh);
            unsigned int cnt = (old >> sh) & 0xffffu;
            eidx[base[k] + cnt] = __float_as_int(dv[p]);
        }
    }
}

// K4: gather — one wave per node, lane = feature. The node's item list is
// loaded ONCE per 64 items with a coalesced 256 B read into registers;
// per-edge indices come from __shfl (1 LDS-pipe op, not a 200-cyc L2 load).
// Row gathers are fully independent — unroll 8 keeps 8 loads in flight.
// w-items: the lane that loaded the item adds its dinv bits (free).
// t = blockIdx&7 keeps each XCD on one t's xh-slice.
__global__ __launch_bounds__(256) void k_gather(
    const int* __restrict__ eidx, const int* __restrict__ offs,
    const int* __restrict__ dega, const float* __restrict__ dinv,
    const __half* __restrict__ xh, float* __restrict__ v, float* __restrict__ alpha) {
    const int t = blockIdx.x & 7;
    const int n = ((blockIdx.x >> 3) << 2) + (threadIdx.x >> 6);
    const int lane = threadIdx.x & 63;
    if (n >= N) return;
    const int node = t * N + n;
    const int start = offs[node];
    const int end = offs[node + 1];
    const int aggEnd = start + dega[node];
    const __half* xt = xh + (size_t)t * N * 64;
    float acc = 0.f;
    float wsum = 0.f;
    for (int bs = start; bs < end; bs += 64) {
        int cnt = end - bs; if (cnt > 64) cnt = 64;
        int idx = 0;
        if (lane < cnt) idx = __builtin_nontemporal_load(&eidx[bs + lane]);
        int na = aggEnd - bs;
        if (na > cnt) na = cnt;
        if (na < 0) na = 0;
        int e = 0;
        for (; e + 7 < na; e += 8) {
            int o0 = __shfl(idx, e + 0), o1 = __shfl(idx, e + 1);
            int o2 = __shfl(idx, e + 2), o3 = __shfl(idx, e + 3);
            int o4 = __shfl(idx, e + 4), o5 = __shfl(idx, e + 5);
            int o6 = __shfl(idx, e + 6), o7 = __shfl(idx, e + 7);
            float x0 = __half2float(xt[o0 + lane]);
            float x1 = __half2float(xt[o1 + lane]);
            float x2 = __half2float(xt[o2 + lane]);
            float x3 = __half2float(xt[o3 + lane]);
            float x4 = __half2float(xt[o4 + lane]);
            float x5 = __half2float(xt[o5 + lane]);
            float x6 = __half2float(xt[o6 + lane]);
            float x7 = __half2float(xt[o7 + lane]);
            acc += ((x0 + x1) + (x2 + x3)) + ((x4 + x5) + (x6 + x7));
        }
        for (; e < na; e++) {
            int o = __shfl(idx, e);
            acc += __half2float(xt[o + lane]);
        }
        if (lane >= na && lane < cnt) wsum += __int_as_float(idx);
    }
#pragma unroll
    for (int off = 32; off > 0; off >>= 1) wsum += __shfl_down(wsum, off);
    wsum = __shfl(wsum, 0);
    float di = dinv[node];
    v[(size_t)node * 64 + lane] = di * (acc + __half2float(xt[(n << 6) + lane]));
    if (lane == 0) alpha[node] = di * (wsum + di);
}

// K5: per-node layer-1 GEMM (64->128), BN1 + ReLU, alpha-weighted pool.
__global__ __launch_bounds__(256) void k_gemm_pool(
    const float* __restrict__ v, const float* __restrict__ alpha,
    const float* __restrict__ W1, const float* __restrict__ b1,
    const float* __restrict__ g1, const float* __restrict__ be1,
    const float* __restrict__ m1, const float* __restrict__ v1,
    float* __restrict__ pooled) {
    __shared__ float Ws[64 * 128];          // [k][j]
    __shared__ float sb[128], st[128], pool[128];
    const int t = blockIdx.y;
    const int tid = threadIdx.x;
    const int n = blockIdx.x * 256 + tid;

    for (int i = tid; i < 64 * 128; i += 256) Ws[i] = W1[i];
    if (tid < 128) {
        float s = g1[tid] * rsqrtf(v1[tid] + EPS);
        sb[tid] = s;
        st[tid] = s * b1[tid] + be1[tid] - m1[tid] * s;
        pool[tid] = 0.0f;
    }
    __syncthreads();

    float vv[64];
    float al = 0.0f;
    if (n < N) {
        int node = t * N + n;
        al = alpha[node];
        const float4* v4 = (const float4*)(v + (size_t)node * 64);
#pragma unroll
        for (int k4 = 0; k4 < 16; k4++) {
            float4 a = v4[k4];
            vv[4 * k4 + 0] = a.x; vv[4 * k4 + 1] = a.y;
            vv[4 * k4 + 2] = a.z; vv[4 * k4 + 3] = a.w;
        }
    } else {
#pragma unroll
        for (int k = 0; k < 64; k++) vv[k] = 0.0f;
    }

    const int lane = tid & 63;
    for (int j4 = 0; j4 < 32; j4++) {
        float s0 = 0.f, s1 = 0.f, s2 = 0.f, s3 = 0.f;
#pragma unroll
        for (int k = 0; k < 64; k++) {
            float4 wv = *(const float4*)&Ws[k * 128 + j4 * 4];
            s0 += vv[k] * wv.x;
            s1 += vv[k] * wv.y;
            s2 += vv[k] * wv.z;
            s3 += vv[k] * wv.w;
        }
        int j = j4 * 4;
        float y0 = fmaxf(sb[j + 0] * s0 + st[j + 0], 0.f) * al;
        float y1 = fmaxf(sb[j + 1] * s1 + st[j + 1], 0.f) * al;
        float y2 = fmaxf(sb[j + 2] * s2 + st[j + 2], 0.f) * al;
        float y3 = fmaxf(sb[j + 3] * s3 + st[j + 3], 0.f) * al;
#pragma unroll
        for (int off = 32; off > 0; off >>= 1) {
            y0 += __shfl_down(y0, off);
            y1 += __shfl_down(y1, off);
            y2 += __shfl_down(y2, off);
            y3 += __shfl_down(y3, off);
        }
        if (lane == 0) {
            atomicAdd(&pool[j + 0], y0);
            atomicAdd(&pool[j + 1], y1);
            atomicAdd(&pool[j + 2], y2);
            atomicAdd(&pool[j + 3], y3);
        }
    }
    __syncthreads();
    if (tid < 128) atomicAdd(&pooled[t * 128 + tid], pool[tid]);
}

// K6a: warm every XCD's L2 with the recurrence weights (768 KB).
__global__ __launch_bounds__(256) void k_warm(const float* __restrict__ a,
                                              const float* __restrict__ b,
                                              const float* __restrict__ c,
                                              float* __restrict__ sink) {
    int slice = blockIdx.x >> 3;           // 0..7, 24576 floats each
    int start = slice * 24576;
    float s = 0.f;
    for (int i = start + threadIdx.x; i < start + 24576; i += 256) {
        float v;
        if (i < 65536) v = a[i];
        else if (i < 131072) v = b[i - 65536];
        else v = c[i - 131072];
        s += v;
    }
    sink[blockIdx.x * 256 + threadIdx.x] = s;
}

// K6b: emb = bn2(pooled/N @ W2 + b2) and layer-0 x-part gates.
__global__ __launch_bounds__(512) void k_emb(
    const float* __restrict__ pooled,
    const float* __restrict__ W2, const float* __restrict__ b2,
    const float* __restrict__ g2, const float* __restrict__ be2,
    const float* __restrict__ m2, const float* __restrict__ v2,
    const float* __restrict__ Wih0, const float* __restrict__ bih0,
    const float* __restrict__ bhh0, float* __restrict__ gx0_g) {
    const int t = blockIdx.x, tid = threadIdx.x;
    __shared__ float pm[128];
    __shared__ float es[128];
    if (tid < 128) pm[tid] = pooled[t * 128 + tid] * (1.0f / N);
    __syncthreads();
    if (tid < 128) {
        float s = g2[tid] * rsqrtf(v2[tid] + EPS);
        float sh = be2[tid] - m2[tid] * s;
        float dot = 0.f;
#pragma unroll 8
        for (int k = 0; k < 128; k++) dot += pm[k] * W2[k * 128 + tid];
        es[tid] = s * (dot + b2[tid]) + sh;
    }
    __syncthreads();
    float dot = bih0[tid] + bhh0[tid];
    const float4* w = (const float4*)(Wih0 + tid * 128);
    const float4* e4 = (const float4*)es;
#pragma unroll
    for (int k4 = 0; k4 < 32; k4++) {
        float4 a = w[k4], bb = e4[k4];
        dot += a.x * bb.x + a.y * bb.y + a.z * bb.z + a.w * bb.w;
    }
    gx0_g[t * 512 + tid] = dot;
}

// K6c: single block, 1024 threads. Thread (r = tid&511, hf = tid>>9) owns a
// HALF gate row (16 float4 = 64 VGPRs). Halves combine through LDS part[].
__global__ __launch_bounds__(1024, 4) void k_head(
    const float* __restrict__ gx0_g,
    const float* __restrict__ Whh0, const float* __restrict__ Whh1,
    const float* __restrict__ Wih1, const float* __restrict__ bih1,
    const float* __restrict__ bhh1,
    const float* __restrict__ Wc, const float* __restrict__ bc,
    float* __restrict__ out) {
    __shared__ float gx0[T][512];
    __shared__ float gx1h[2][T][512];
    __shared__ float ys[T][128];
    __shared__ float h[128];
    __shared__ float part[1024];
    const int tid = threadIdx.x;
    const int r = tid & 511, hf = tid >> 9;

    for (int i = tid; i < T * 512; i += 1024) gx0[i >> 9][i & 511] = gx0_g[i];
    if (tid < 128) h[tid] = 0.f;

    float4 w[16];
    {
        const float4* p = (const float4*)(Whh0 + r * 128 + hf * 64);
#pragma unroll
        for (int k = 0; k < 16; k++) w[k] = p[k];
    }
    float c = 0.f;
    __syncthreads();

    // LSTM layer 0
    for (int t = 0; t < T; t++) {
        const float4* h4 = ((const float4*)h) + hf * 16;
        float dot = 0.f;
#pragma unroll
        for (int k = 0; k < 16; k++) {
            float4 hv = h4[k];
            dot += w[k].x * hv.x + w[k].y * hv.y + w[k].z * hv.z + w[k].w * hv.w;
        }
        part[tid] = dot;
        __syncthreads();
        if (tid < 128) {
            float i_ = gx0[t][tid]       + part[tid]       + part[512 + tid];
            float f_ = gx0[t][128 + tid] + part[128 + tid] + part[640 + tid];
            float g_ = gx0[t][256 + tid] + part[256 + tid] + part[768 + tid];
            float o_ = gx0[t][384 + tid] + part[384 + tid] + part[896 + tid];
            c = sigm(f_) * c + sigm(i_) * tanhf(g_);
            float hv = sigm(o_) * tanhf(c);
            h[tid] = hv;
            ys[t][tid] = hv;
        }
        __syncthreads();
    }

    // gx1 halves
    {
        const float4* p = (const float4*)(Wih1 + r * 128 + hf * 64);
#pragma unroll
        for (int k = 0; k < 16; k++) w[k] = p[k];
        float bias = (hf == 0) ? (bih1[r] + bhh1[r]) : 0.f;
        for (int t = 0; t < T; t++) {
            const float4* y4 = ((const float4*)ys[t]) + hf * 16;
            float dot = bias;
#pragma unroll
            for (int k = 0; k < 16; k++) {
                float4 yv = y4[k];
                dot += w[k].x * yv.x + w[k].y * yv.y + w[k].z * yv.z + w[k].w * yv.w;
            }
            gx1h[hf][t][r] = dot;
        }
    }

    // LSTM layer 1
    {
        const float4* p = (const float4*)(Whh1 + r * 128 + hf * 64);
#pragma unroll
        for (int k = 0; k < 16; k++) w[k] = p[k];
    }
    if (tid < 128) h[tid] = 0.f;
    c = 0.f;
    __syncthreads();
    for (int t = 0; t < T; t++) {
        const float4* h4 = ((const float4*)h) + hf * 16;
        float dot = 0.f;
#pragma unroll
        for (int k = 0; k < 16; k++) {
            float4 hv = h4[k];
            dot += w[k].x * hv.x + w[k].y * hv.y + w[k].z * hv.z + w[k].w * hv.w;
        }
        part[tid] = dot;
        __syncthreads();
        if (tid < 128) {
            float i_ = gx1h[0][t][tid]       + gx1h[1][t][tid]       + part[tid]       + part[512 + tid];
            float f_ = gx1h[0][t][128 + tid] + gx1h[1][t][128 + tid] + part[128 + tid] + part[640 + tid];
            float g_ = gx1h[0][t][256 + tid] + gx1h[1][t][256 + tid] + part[256 + tid] + part[768 + tid];
            float o_ = gx1h[0][t][384 + tid] + gx1h[1][t][384 + tid] + part[384 + tid] + part[896 + tid];
            c = sigm(f_) * c + sigm(i_) * tanhf(g_);
            h[tid] = sigm(o_) * tanhf(c);
        }
        __syncthreads();
    }

    if (tid < 2) {
        float dot = bc[tid];
#pragma unroll 8
        for (int k = 0; k < 128; k++) dot += h[k] * Wc[tid * 128 + k];
        out[tid] = dot;
    }
    if (tid < 128) out[2 + tid] = h[tid];
}

// ---------------------------------------------------------------------------
extern "C" void kernel_launch(void* const* d_in, const int* in_sizes, int n_in,
                              void* d_out, int out_size, void* d_ws, size_t ws_size,
                              hipStream_t stream) {
    const float* x    = (const float*)d_in[0];
    const int*   edges= (const int*)d_in[1];
    const float* W1   = (const float*)d_in[2];
    const float* b1   = (const float*)d_in[3];
    const float* g1   = (const float*)d_in[4];
    const float* be1  = (const float*)d_in[5];
    const float* m1   = (const float*)d_in[6];
    const float* v1   = (const float*)d_in[7];
    const float* W2   = (const float*)d_in[8];
    const float* b2   = (const float*)d_in[9];
    const float* g2   = (const float*)d_in[10];
    const float* be2  = (const float*)d_in[11];
    const float* m2   = (const float*)d_in[12];
    const float* v2   = (const float*)d_in[13];
    const float* Wih0 = (const float*)d_in[14];
    const float* Whh0 = (const float*)d_in[15];
    const float* bih0 = (const float*)d_in[16];
    const float* bhh0 = (const float*)d_in[17];
    const float* Wih1 = (const float*)d_in[18];
    const float* Whh1 = (const float*)d_in[19];
    const float* bih1 = (const float*)d_in[20];
    const float* bhh1 = (const float*)d_in[21];
    const float* Wc   = (const float*)d_in[22];
    const float* bc   = (const float*)d_in[23];

    char* base = (char*)d_ws;
    // v (41 MB) aliases hist_g (10.24 MB) + base_g (20.48 MB): hist dead after
    // k_base, base_g dead after k_fill, v written in k_gather — safe ordering.
    float*        v      = (float*)base;                              // T*N*64 f32
    unsigned int* hist_g = (unsigned int*)base;                       // T*NB*NPACK u32
    unsigned int* base_g = (unsigned int*)(base + (size_t)T * NB * NPACK * 4);
    char* p = base + (size_t)T * N * 64 * 4;
    __half* xh   = (__half*)p;              p += (size_t)T * N * 64 * 2;  // 20.5 MB
    int*   offs  = (int*)p;                 p += (size_t)(T * N + 1) * 4 + 12; // keep 16B align
    int*   dega  = (int*)p;                 p += (size_t)T * N * 4;
    float* dinv  = (float*)p;               p += (size_t)T * N * 4;
    float* alpha = (float*)p;               p += (size_t)T * N * 4;
    int*   tot   = (int*)p;                 p += (size_t)T * N * 4;   // reused as warm sink
    int*   eidx  = (int*)p;                 p += (size_t)T * 2 * E * 4;
    float* pooled= (float*)p;               p += (size_t)T * 128 * 4;
    float* gx0_g = (float*)p;

    (void)hipMemsetAsync(pooled, 0, T * 128 * sizeof(float), stream);

    dim3 gs(T, NB);
    k_hist<<<gs, 1024, 0, stream>>>(edges, hist_g);
    k_colsum<<<(T * NPACK + 255) / 256, 256, 0, stream>>>(hist_g, tot, dega, dinv);
    k_scanN<<<T, 1024, 0, stream>>>(tot, offs);
    k_base<<<(T * N + 255) / 256, 256, 0, stream>>>(hist_g, offs, base_g);
    k_cvt<<<(T * N * 16 + 255) / 256, 256, 0, stream>>>(x, dinv, xh);
    k_fill<<<gs, 1024, 0, stream>>>(edges, base_g, dinv, eidx);
    k_gather<<<(T * N) / 4, 256, 0, stream>>>(eidx, offs, dega, dinv, xh, v, alpha);

    dim3 g4((N + 255) / 256, T);
    k_gemm_pool<<<g4, 256, 0, stream>>>(v, alpha, W1, b1, g1, be1, m1, v1, pooled);

    k_warm<<<64, 256, 0, stream>>>(Whh0, Whh1, Wih1, (float*)tot);
    k_emb<<<T, 512, 0, stream>>>(pooled, W2, b2, g2, be2, m2, v2, Wih0, bih0, bhh0, gx0_g);
    k_head<<<1, 1024, 0, stream>>>(gx0_g, Whh0, Whh1, Wih1, bih1, bhh1, Wc, bc, (float*)d_out);
}

// Round 14
// 451.528 us; speedup vs baseline: 1.2605x; 1.1089x over previous
//
#include <hip/hip_runtime.h>
#include <hip/hip_fp16.h>
#include <math.h>

#define T 8
#define N 20000
#define E 320000
#define EPS 1e-5f
#define NB 32          // item-sort blocks per t: 16 agg-half + 16 w-half
#define CHUNK 20000    // E/16 items per block
#define NPACK 10000    // N/2 packed u32 (2 x u16 counters)
#define TILES_PT 1250  // 16-node MFMA tiles per t

typedef _Float16 f16x8 __attribute__((ext_vector_type(8)));
typedef float f32x4 __attribute__((ext_vector_type(4)));

__device__ __forceinline__ float sigm(float x) { return 1.0f / (1.0f + expf(-x)); }

// ---------------------------------------------------------------------------
// K0: W1t[j][k] = half(W1[k][j])  (fp16 transposed weights for MFMA B-frags)
__global__ __launch_bounds__(256) void k_prepw(const float* __restrict__ W1,
                                               __half* __restrict__ W1t) {
    int i = blockIdx.x * 256 + threadIdx.x;
    if (i >= 64 * 128) return;
    int j = i & 127, k = i >> 7;
    W1t[j * 64 + k] = __float2half(W1[i]);
}

// K1: per-(t,block) LDS histogram of item keys. b<16: dst over agg items;
// b>=16: src over w items.
__global__ __launch_bounds__(1024) void k_hist(const int* __restrict__ edges,
                                               unsigned int* __restrict__ hist_g) {
    __shared__ unsigned int h32[NPACK];
    const int t = blockIdx.x, b = blockIdx.y;
    const int tid = threadIdx.x;
    for (int i = tid; i < NPACK; i += 1024) h32[i] = 0;
    __syncthreads();
    const bool isAgg = (b < 16);
    const int cs = (isAgg ? b : b - 16) * CHUNK;
    const int* keys = edges + (size_t)t * 2 * E + (isAgg ? E : 0) + cs;
    for (int i = tid; i < CHUNK; i += 1024) {
        int k = keys[i];
        atomicAdd(&h32[k >> 1], 1u << ((k & 1) * 16));
    }
    __syncthreads();
    unsigned int* out = hist_g + (size_t)(t * NB + b) * NPACK;
    for (int i = tid; i < NPACK; i += 1024) out[i] = h32[i];
}

// K2a: column sum over the 32 blocks — one thread per packed key pair.
__global__ __launch_bounds__(256) void k_colsum(
    const unsigned int* __restrict__ hist_g, int* __restrict__ tot,
    int* __restrict__ dega, float* __restrict__ dinv) {
    int idx = blockIdx.x * 256 + threadIdx.x;
    if (idx >= T * NPACK) return;
    int t = idx / NPACK, i = idx - t * NPACK;
    const unsigned int* hp = hist_g + (size_t)t * NB * NPACK + i;
    unsigned int a0 = 0, a1 = 0, w0 = 0, w1 = 0;
#pragma unroll
    for (int b = 0; b < 16; b++) {
        unsigned int h = hp[(size_t)b * NPACK];
        a0 += h & 0xffffu; a1 += h >> 16;
    }
#pragma unroll
    for (int b = 16; b < 32; b++) {
        unsigned int h = hp[(size_t)b * NPACK];
        w0 += h & 0xffffu; w1 += h >> 16;
    }
    int n0 = t * N + 2 * i;
    tot[n0]     = (int)(a0 + w0);
    tot[n0 + 1] = (int)(a1 + w1);
    dega[n0]     = (int)a0;
    dega[n0 + 1] = (int)a1;
    dinv[n0]     = rsqrtf((float)a0 + 1.0f);
    dinv[n0 + 1] = rsqrtf((float)a1 + 1.0f);
}

// K2b: per-t exclusive prefix over 20000 node totals -> offs (+ sentinel).
__global__ __launch_bounds__(1024) void k_scanN(const int* __restrict__ tot,
                                                int* __restrict__ offs) {
    const int t = blockIdx.x, tid = threadIdx.x;
    __shared__ int sh[1024];
    int local[20];
    int sum = 0;
    if (tid < 1000) {
        const int* tp = tot + t * N + tid * 20;
#pragma unroll
        for (int i = 0; i < 20; i++) { local[i] = tp[i]; sum += local[i]; }
    }
    sh[tid] = sum;
    __syncthreads();
    for (int off = 1; off < 1024; off <<= 1) {
        int v = (tid >= off) ? sh[tid - off] : 0;
        __syncthreads();
        sh[tid] += v;
        __syncthreads();
    }
    if (tid < 1000) {
        int run = t * 2 * E + sh[tid] - sum;
        int* op = offs + t * N + tid * 20;
#pragma unroll
        for (int i = 0; i < 20; i++) { op[i] = run; run += local[i]; }
    }
    if (t == T - 1 && tid == 0) offs[T * N] = 2 * T * E;
}

// K2c: per-node running prefix over the 32 blocks -> base_g.
__global__ __launch_bounds__(256) void k_base(
    const unsigned int* __restrict__ hist_g, const int* __restrict__ offs,
    unsigned int* __restrict__ base_g) {
    int node = blockIdx.x * 256 + threadIdx.x;
    if (node >= T * N) return;
    int t = node / N, n = node - t * N;
    const unsigned short* h16 = (const unsigned short*)hist_g;
    int run = offs[node];
#pragma unroll
    for (int b = 0; b < NB; b++) {
        size_t o = (size_t)(t * NB + b) * N + n;
        base_g[o] = (unsigned int)run;
        run += h16[o];
    }
}

// K2d: xh[t][n][k] = half(dinv[t][n] * x[t][n][k]). per-t slice 2.56 MB.
__global__ __launch_bounds__(256) void k_cvt(const float* __restrict__ x,
                                             const float* __restrict__ dinv,
                                             __half* __restrict__ xh) {
    int idx = blockIdx.x * 256 + threadIdx.x;   // one float4 per thread
    if (idx >= T * N * 16) return;
    float d = dinv[idx >> 4];
    float4 vv = ((const float4*)x)[idx];
    __half h0 = __float2half(vv.x * d);
    __half h1 = __float2half(vv.y * d);
    __half h2 = __float2half(vv.z * d);
    __half h3 = __float2half(vv.w * d);
    ushort4 pack;
    pack.x = *(unsigned short*)&h0;
    pack.y = *(unsigned short*)&h1;
    pack.z = *(unsigned short*)&h2;
    pack.w = *(unsigned short*)&h3;
    ((ushort4*)xh)[idx] = pack;
}

// K3: fill. Linear grid, t = blockIdx&7 -> all 32 blocks of a t share one
// XCD so the 2.56 MB eidx t-slice stays in that XCD's L2 (kills the 233 MB
// cross-XCD writeback ping-pong).
//   agg item -> eidx = src*64 (row element offset)
//   w   item -> eidx = float bits of dinv[dst]
__global__ __launch_bounds__(1024) void k_fill(const int* __restrict__ edges,
                                               const unsigned int* __restrict__ base_g,
                                               const float* __restrict__ dinv,
                                               int* __restrict__ eidx) {
    __shared__ unsigned int c32[NPACK];
    const int t = blockIdx.x & 7, b = blockIdx.x >> 3;
    const int tid = threadIdx.x;
    for (int i = tid; i < NPACK; i += 1024) c32[i] = 0;
    __syncthreads();
    const bool isAgg = (b < 16);
    const int cs = (isAgg ? b : b - 16) * CHUNK;
    const int* keys = edges + (size_t)t * 2 * E + (isAgg ? E : 0) + cs;
    const int* pays = edges + (size_t)t * 2 * E + (isAgg ? 0 : E) + cs;
    const unsigned int* base = base_g + (size_t)(t * NB + b) * N;
    const float* dv = dinv + t * N;
    if (isAgg) {
        for (int i = tid; i < CHUNK; i += 1024) {
            int k = keys[i];
            int p = pays[i];
            unsigned int sh = (unsigned int)((k & 1) * 16);
            unsigned int old = atomicAdd(&c32[k >> 1], 1u << sh);
            unsigned int cnt = (old >> sh) & 0xffffu;
            eidx[base[k] + cnt] = p << 6;
        }
    } else {
        for (int i = tid; i < CHUNK; i += 1024) {
            int k = keys[i];
            int p = pays[i];
            unsigned int sh = (unsigned int)((k & 1) * 16);
            unsigned int old = atomicAdd(&c32[k >> 1], 1u << sh);
            unsigned int cnt = (old >> sh) & 0xffffu;
            eidx[base[k] + cnt] = __float_as_int(dv[p]);
        }
    }
}

// K4: gather — one wave per node, lane = feature. Item list loaded once per
// 64 items (coalesced); per-edge indices via __shfl; unroll 8 keeps 8 row
// loads in flight. Emits fp16 operand vh and fp32 alpha.
__global__ __launch_bounds__(256) void k_gather(
    const int* __restrict__ eidx, const int* __restrict__ offs,
    const int* __restrict__ dega, const float* __restrict__ dinv,
    const __half* __restrict__ xh, __half* __restrict__ vh, float* __restrict__ alpha) {
    const int t = blockIdx.x & 7;
    const int n = ((blockIdx.x >> 3) << 2) + (threadIdx.x >> 6);
    const int lane = threadIdx.x & 63;
    if (n >= N) return;
    const int node = t * N + n;
    const int start = offs[node];
    const int end = offs[node + 1];
    const int aggEnd = start + dega[node];
    const __half* xt = xh + (size_t)t * N * 64;
    float acc = 0.f;
    float wsum = 0.f;
    for (int bs = start; bs < end; bs += 64) {
        int cnt = end - bs; if (cnt > 64) cnt = 64;
        int idx = 0;
        if (lane < cnt) idx = __builtin_nontemporal_load(&eidx[bs + lane]);
        int na = aggEnd - bs;
        if (na > cnt) na = cnt;
        if (na < 0) na = 0;
        int e = 0;
        for (; e + 7 < na; e += 8) {
            int o0 = __shfl(idx, e + 0), o1 = __shfl(idx, e + 1);
            int o2 = __shfl(idx, e + 2), o3 = __shfl(idx, e + 3);
            int o4 = __shfl(idx, e + 4), o5 = __shfl(idx, e + 5);
            int o6 = __shfl(idx, e + 6), o7 = __shfl(idx, e + 7);
            float x0 = __half2float(xt[o0 + lane]);
            float x1 = __half2float(xt[o1 + lane]);
            float x2 = __half2float(xt[o2 + lane]);
            float x3 = __half2float(xt[o3 + lane]);
            float x4 = __half2float(xt[o4 + lane]);
            float x5 = __half2float(xt[o5 + lane]);
            float x6 = __half2float(xt[o6 + lane]);
            float x7 = __half2float(xt[o7 + lane]);
            acc += ((x0 + x1) + (x2 + x3)) + ((x4 + x5) + (x6 + x7));
        }
        for (; e < na; e++) {
            int o = __shfl(idx, e);
            acc += __half2float(xt[o + lane]);
        }
        if (lane >= na && lane < cnt) wsum += __int_as_float(idx);
    }
#pragma unroll
    for (int off = 32; off > 0; off >>= 1) wsum += __shfl_down(wsum, off);
    wsum = __shfl(wsum, 0);
    float di = dinv[node];
    vh[(size_t)node * 64 + lane] =
        __float2half(di * (acc + __half2float(xt[(n << 6) + lane])));
    if (lane == 0) alpha[node] = di * (wsum + di);
}

// K5: MFMA layer-1 GEMM (fp16 in, fp32 acc) + BN/ReLU + alpha-pool.
// One wave handles 8 node-tiles of 16 nodes; W1 B-fragments live in
// registers for the whole wave (zero LDS). C/D layout: col=lane&15,
// row=(lane>>4)*4+reg (guide §3, m89-verified, dtype-independent).
__global__ __launch_bounds__(256) void k_mfma_pool(
    const __half* __restrict__ vh, const float* __restrict__ alpha,
    const __half* __restrict__ W1t,
    const float* __restrict__ b1, const float* __restrict__ g1,
    const float* __restrict__ be1, const float* __restrict__ m1,
    const float* __restrict__ v1, float* __restrict__ pooled) {
    const int t = blockIdx.x & 7;
    const int bt = blockIdx.x >> 3;
    const int w = threadIdx.x >> 6, lane = threadIdx.x & 63;
    const int q = lane >> 4, col = lane & 15;
    const size_t tb = (size_t)t * N;

    f16x8 bfr[8][2];
    float sbv[8], stv[8];
#pragma unroll
    for (int jt = 0; jt < 8; jt++) {
        int j = jt * 16 + col;
        float s = g1[j] * rsqrtf(v1[j] + EPS);
        sbv[jt] = s;
        stv[jt] = s * b1[j] + be1[j] - m1[j] * s;
#pragma unroll
        for (int kk = 0; kk < 2; kk++)
            bfr[jt][kk] = *(const f16x8*)(W1t + (size_t)j * 64 + kk * 32 + q * 8);
    }
    float pool8[8];
#pragma unroll
    for (int jt = 0; jt < 8; jt++) pool8[jt] = 0.f;

    for (int i = 0; i < 8; i++) {
        int tau = bt * 32 + w * 8 + i;
        if (tau >= TILES_PT) break;
        int nb = tau * 16;
        const __half* vrow = vh + (tb + nb + col) * 64;
        f16x8 a0 = *(const f16x8*)(vrow + q * 8);
        f16x8 a1 = *(const f16x8*)(vrow + 32 + q * 8);
        float4 af = ((const float4*)(alpha + tb + nb))[q];  // alpha rows q*4..q*4+3
#pragma unroll
        for (int jt = 0; jt < 8; jt++) {
            f32x4 acc = {0.f, 0.f, 0.f, 0.f};
            acc = __builtin_amdgcn_mfma_f32_16x16x32_f16(a0, bfr[jt][0], acc, 0, 0, 0);
            acc = __builtin_amdgcn_mfma_f32_16x16x32_f16(a1, bfr[jt][1], acc, 0, 0, 0);
            float s = sbv[jt], sh = stv[jt];
            pool8[jt] += fmaxf(s * acc[0] + sh, 0.f) * af.x
                       + fmaxf(s * acc[1] + sh, 0.f) * af.y
                       + fmaxf(s * acc[2] + sh, 0.f) * af.z
                       + fmaxf(s * acc[3] + sh, 0.f) * af.w;
        }
    }
#pragma unroll
    for (int jt = 0; jt < 8; jt++) {
        pool8[jt] += __shfl_xor(pool8[jt], 16);
        pool8[jt] += __shfl_xor(pool8[jt], 32);
    }
    if (lane < 16) {
#pragma unroll
        for (int jt = 0; jt < 8; jt++)
            atomicAdd(&pooled[t * 128 + jt * 16 + lane], pool8[jt]);
    }
}

// K6a: warm every XCD's L2 with the recurrence weights (768 KB).
__global__ __launch_bounds__(256) void k_warm(const float* __restrict__ a,
                                              const float* __restrict__ b,
                                              const float* __restrict__ c,
                                              float* __restrict__ sink) {
    int slice = blockIdx.x >> 3;           // 0..7, 24576 floats each
    int start = slice * 24576;
    float s = 0.f;
    for (int i = start + threadIdx.x; i < start + 24576; i += 256) {
        float v;
        if (i < 65536) v = a[i];
        else if (i < 131072) v = b[i - 65536];
        else v = c[i - 131072];
        s += v;
    }
    sink[blockIdx.x * 256 + threadIdx.x] = s;
}

// K6b: emb = bn2(pooled/N @ W2 + b2) and layer-0 x-part gates.
__global__ __launch_bounds__(512) void k_emb(
    const float* __restrict__ pooled,
    const float* __restrict__ W2, const float* __restrict__ b2,
    const float* __restrict__ g2, const float* __restrict__ be2,
    const float* __restrict__ m2, const float* __restrict__ v2,
    const float* __restrict__ Wih0, const float* __restrict__ bih0,
    const float* __restrict__ bhh0, float* __restrict__ gx0_g) {
    const int t = blockIdx.x, tid = threadIdx.x;
    __shared__ float pm[128];
    __shared__ float es[128];
    if (tid < 128) pm[tid] = pooled[t * 128 + tid] * (1.0f / N);
    __syncthreads();
    if (tid < 128) {
        float s = g2[tid] * rsqrtf(v2[tid] + EPS);
        float sh = be2[tid] - m2[tid] * s;
        float dot = 0.f;
#pragma unroll 8
        for (int k = 0; k < 128; k++) dot += pm[k] * W2[k * 128 + tid];
        es[tid] = s * (dot + b2[tid]) + sh;
    }
    __syncthreads();
    float dot = bih0[tid] + bhh0[tid];
    const float4* w = (const float4*)(Wih0 + tid * 128);
    const float4* e4 = (const float4*)es;
#pragma unroll
    for (int k4 = 0; k4 < 32; k4++) {
        float4 a = w[k4], bb = e4[k4];
        dot += a.x * bb.x + a.y * bb.y + a.z * bb.z + a.w * bb.w;
    }
    gx0_g[t * 512 + tid] = dot;
}

// K6c: single block, 1024 threads. Thread (r = tid&511, hf = tid>>9) owns a
// HALF gate row (16 float4 = 64 VGPRs). Halves combine through LDS part[].
__global__ __launch_bounds__(1024, 4) void k_head(
    const float* __restrict__ gx0_g,
    const float* __restrict__ Whh0, const float* __restrict__ Whh1,
    const float* __restrict__ Wih1, const float* __restrict__ bih1,
    const float* __restrict__ bhh1,
    const float* __restrict__ Wc, const float* __restrict__ bc,
    float* __restrict__ out) {
    __shared__ float gx0[T][512];
    __shared__ float gx1h[2][T][512];
    __shared__ float ys[T][128];
    __shared__ float h[128];
    __shared__ float part[1024];
    const int tid = threadIdx.x;
    const int r = tid & 511, hf = tid >> 9;

    for (int i = tid; i < T * 512; i += 1024) gx0[i >> 9][i & 511] = gx0_g[i];
    if (tid < 128) h[tid] = 0.f;

    float4 w[16];
    {
        const float4* p = (const float4*)(Whh0 + r * 128 + hf * 64);
#pragma unroll
        for (int k = 0; k < 16; k++) w[k] = p[k];
    }
    float c = 0.f;
    __syncthreads();

    // LSTM layer 0
    for (int t = 0; t < T; t++) {
        const float4* h4 = ((const float4*)h) + hf * 16;
        float dot = 0.f;
#pragma unroll
        for (int k = 0; k < 16; k++) {
            float4 hv = h4[k];
            dot += w[k].x * hv.x + w[k].y * hv.y + w[k].z * hv.z + w[k].w * hv.w;
        }
        part[tid] = dot;
        __syncthreads();
        if (tid < 128) {
            float i_ = gx0[t][tid]       + part[tid]       + part[512 + tid];
            float f_ = gx0[t][128 + tid] + part[128 + tid] + part[640 + tid];
            float g_ = gx0[t][256 + tid] + part[256 + tid] + part[768 + tid];
            float o_ = gx0[t][384 + tid] + part[384 + tid] + part[896 + tid];
            c = sigm(f_) * c + sigm(i_) * tanhf(g_);
            float hv = sigm(o_) * tanhf(c);
            h[tid] = hv;
            ys[t][tid] = hv;
        }
        __syncthreads();
    }

    // gx1 halves
    {
        const float4* p = (const float4*)(Wih1 + r * 128 + hf * 64);
#pragma unroll
        for (int k = 0; k < 16; k++) w[k] = p[k];
        float bias = (hf == 0) ? (bih1[r] + bhh1[r]) : 0.f;
        for (int t = 0; t < T; t++) {
            const float4* y4 = ((const float4*)ys[t]) + hf * 16;
            float dot = bias;
#pragma unroll
            for (int k = 0; k < 16; k++) {
                float4 yv = y4[k];
                dot += w[k].x * yv.x + w[k].y * yv.y + w[k].z * yv.z + w[k].w * yv.w;
            }
            gx1h[hf][t][r] = dot;
        }
    }

    // LSTM layer 1
    {
        const float4* p = (const float4*)(Whh1 + r * 128 + hf * 64);
#pragma unroll
        for (int k = 0; k < 16; k++) w[k] = p[k];
    }
    if (tid < 128) h[tid] = 0.f;
    c = 0.f;
    __syncthreads();
    for (int t = 0; t < T; t++) {
        const float4* h4 = ((const float4*)h) + hf * 16;
        float dot = 0.f;
#pragma unroll
        for (int k = 0; k < 16; k++) {
            float4 hv = h4[k];
            dot += w[k].x * hv.x + w[k].y * hv.y + w[k].z * hv.z + w[k].w * hv.w;
        }
        part[tid] = dot;
        __syncthreads();
        if (tid < 128) {
            float i_ = gx1h[0][t][tid]       + gx1h[1][t][tid]       + part[tid]       + part[512 + tid];
            float f_ = gx1h[0][t][128 + tid] + gx1h[1][t][128 + tid] + part[128 + tid] + part[640 + tid];
            float g_ = gx1h[0][t][256 + tid] + gx1h[1][t][256 + tid] + part[256 + tid] + part[768 + tid];
            float o_ = gx1h[0][t][384 + tid] + gx1h[1][t][384 + tid] + part[384 + tid] + part[896 + tid];
            c = sigm(f_) * c + sigm(i_) * tanhf(g_);
            h[tid] = sigm(o_) * tanhf(c);
        }
        __syncthreads();
    }

    if (tid < 2) {
        float dot = bc[tid];
#pragma unroll 8
        for (int k = 0; k < 128; k++) dot += h[k] * Wc[tid * 128 + k];
        out[tid] = dot;
    }
    if (tid < 128) out[2 + tid] = h[tid];
}

// ---------------------------------------------------------------------------
extern "C" void kernel_launch(void* const* d_in, const int* in_sizes, int n_in,
                              void* d_out, int out_size, void* d_ws, size_t ws_size,
                              hipStream_t stream) {
    const float* x    = (const float*)d_in[0];
    const int*   edges= (const int*)d_in[1];
    const float* W1   = (const float*)d_in[2];
    const float* b1   = (const float*)d_in[3];
    const float* g1   = (const float*)d_in[4];
    const float* be1  = (const float*)d_in[5];
    const float* m1   = (const float*)d_in[6];
    const float* v1   = (const float*)d_in[7];
    const float* W2   = (const float*)d_in[8];
    const float* b2   = (const float*)d_in[9];
    const float* g2   = (const float*)d_in[10];
    const float* be2  = (const float*)d_in[11];
    const float* m2   = (const float*)d_in[12];
    const float* v2   = (const float*)d_in[13];
    const float* Wih0 = (const float*)d_in[14];
    const float* Whh0 = (const float*)d_in[15];
    const float* bih0 = (const float*)d_in[16];
    const float* bhh0 = (const float*)d_in[17];
    const float* Wih1 = (const float*)d_in[18];
    const float* Whh1 = (const float*)d_in[19];
    const float* bih1 = (const float*)d_in[20];
    const float* bhh1 = (const float*)d_in[21];
    const float* Wc   = (const float*)d_in[22];
    const float* bc   = (const float*)d_in[23];

    char* base = (char*)d_ws;
    // Aliasing: hist_g (10.24 MB) + base_g (20.48 MB) occupy [0, 30.72 MB).
    // vh (20.5 MB) aliases that region — hist_g dead after k_base, base_g
    // dead after k_fill, vh written in k_gather (after k_fill). Safe.
    unsigned int* hist_g = (unsigned int*)base;                       // T*NB*NPACK u32
    unsigned int* base_g = (unsigned int*)(base + (size_t)T * NB * NPACK * 4);
    __half*       vh     = (__half*)base;                             // T*N*64 f16
    char* p = base + (size_t)T * NB * NPACK * 4 + (size_t)T * NB * N * 4;
    __half* xh   = (__half*)p;              p += (size_t)T * N * 64 * 2;  // 20.5 MB
    int*   offs  = (int*)p;                 p += (size_t)(T * N + 1) * 4 + 12; // keep 16B align
    int*   dega  = (int*)p;                 p += (size_t)T * N * 4;
    float* dinv  = (float*)p;               p += (size_t)T * N * 4;
    float* alpha = (float*)p;               p += (size_t)T * N * 4;
    int*   tot   = (int*)p;                 p += (size_t)T * N * 4;   // reused as warm sink
    int*   eidx  = (int*)p;                 p += (size_t)T * 2 * E * 4;
    float* pooled= (float*)p;               p += (size_t)T * 128 * 4;
    float* gx0_g = (float*)p;               p += (size_t)T * 512 * 4;
    __half* W1t  = (__half*)p;

    (void)hipMemsetAsync(pooled, 0, T * 128 * sizeof(float), stream);

    k_prepw<<<32, 256, 0, stream>>>(W1, W1t);
    dim3 gs(T, NB);
    k_hist<<<gs, 1024, 0, stream>>>(edges, hist_g);
    k_colsum<<<(T * NPACK + 255) / 256, 256, 0, stream>>>(hist_g, tot, dega, dinv);
    k_scanN<<<T, 1024, 0, stream>>>(tot, offs);
    k_base<<<(T * N + 255) / 256, 256, 0, stream>>>(hist_g, offs, base_g);
    k_cvt<<<(T * N * 16 + 255) / 256, 256, 0, stream>>>(x, dinv, xh);
    k_fill<<<T * NB, 1024, 0, stream>>>(edges, base_g, dinv, eidx);
    k_gather<<<(T * N) / 4, 256, 0, stream>>>(eidx, offs, dega, dinv, xh, vh, alpha);
    k_mfma_pool<<<8 * 40, 256, 0, stream>>>(vh, alpha, W1t, b1, g1, be1, m1, v1, pooled);

    k_warm<<<64, 256, 0, stream>>>(Whh0, Whh1, Wih1, (float*)tot);
    k_emb<<<T, 512, 0, stream>>>(pooled, W2, b2, g2, be2, m2, v2, Wih0, bih0, bhh0, gx0_g);
    k_head<<<1, 1024, 0, stream>>>(gx0_g, Whh0, Whh1, Wih1, bih1, bhh1, Wc, bc, (float*)d_out);
}

// Round 15
// 423.697 us; speedup vs baseline: 1.3433x; 1.0657x over previous
//
#include <hip/hip_runtime.h>
#include <hip/hip_fp16.h>
#include <math.h>

#define T 8
#define N 20000
#define E 320000
#define EPS 1e-5f
#define NBA 32         // agg-item sort blocks per t
#define CHUNKA 10000   // E/32 items per block
#define NPACK 10000    // N/2 packed u32 (2 x u16 counters)
#define TILES_PT 1250  // 16-node MFMA tiles per t

typedef _Float16 f16x8 __attribute__((ext_vector_type(8)));
typedef float f32x4 __attribute__((ext_vector_type(4)));

__device__ __forceinline__ float sigm(float x) { return 1.0f / (1.0f + expf(-x)); }

// ---------------------------------------------------------------------------
// K0: W1t[j][k] = half(W1[k][j])  (fp16 transposed weights for MFMA B-frags)
__global__ __launch_bounds__(256) void k_prepw(const float* __restrict__ W1,
                                               __half* __restrict__ W1t) {
    int i = blockIdx.x * 256 + threadIdx.x;
    if (i >= 64 * 128) return;
    int j = i & 127, k = i >> 7;
    W1t[j * 64 + k] = __float2half(W1[i]);
}

// K1: per-(t,block) LDS histogram of agg-item keys (dst).
__global__ __launch_bounds__(1024) void k_hist(const int* __restrict__ edges,
                                               unsigned int* __restrict__ hist_g) {
    __shared__ unsigned int h32[NPACK];
    const int t = blockIdx.x, b = blockIdx.y;
    const int tid = threadIdx.x;
    for (int i = tid; i < NPACK; i += 1024) h32[i] = 0;
    __syncthreads();
    const int* keys = edges + (size_t)t * 2 * E + E + b * CHUNKA;   // dst half
    for (int i = tid; i < CHUNKA; i += 1024) {
        int k = keys[i];
        atomicAdd(&h32[k >> 1], 1u << ((k & 1) * 16));
    }
    __syncthreads();
    unsigned int* out = hist_g + (size_t)(t * NBA + b) * NPACK;
    for (int i = tid; i < NPACK; i += 1024) out[i] = h32[i];
}

// K2a: column sum over the 32 agg blocks — one thread per packed key pair.
// dega = in-degree; dinv = rsqrt(deg+1).
__global__ __launch_bounds__(256) void k_colsum(
    const unsigned int* __restrict__ hist_g,
    int* __restrict__ dega, float* __restrict__ dinv) {
    int idx = blockIdx.x * 256 + threadIdx.x;
    if (idx >= T * NPACK) return;
    int t = idx / NPACK, i = idx - t * NPACK;
    const unsigned int* hp = hist_g + (size_t)t * NBA * NPACK + i;
    unsigned int a0 = 0, a1 = 0;
#pragma unroll
    for (int b = 0; b < NBA; b++) {
        unsigned int h = hp[(size_t)b * NPACK];
        a0 += h & 0xffffu; a1 += h >> 16;
    }
    int n0 = t * N + 2 * i;
    dega[n0]     = (int)a0;
    dega[n0 + 1] = (int)a1;
    dinv[n0]     = rsqrtf((float)a0 + 1.0f);
    dinv[n0 + 1] = rsqrtf((float)a1 + 1.0f);
}

// K2b: per-t exclusive prefix over node in-degrees -> offs (+ sentinel).
__global__ __launch_bounds__(1024) void k_scanN(const int* __restrict__ dega,
                                                int* __restrict__ offs) {
    const int t = blockIdx.x, tid = threadIdx.x;
    __shared__ int sh[1024];
    int local[20];
    int sum = 0;
    if (tid < 1000) {
        const int* tp = dega + t * N + tid * 20;
#pragma unroll
        for (int i = 0; i < 20; i++) { local[i] = tp[i]; sum += local[i]; }
    }
    sh[tid] = sum;
    __syncthreads();
    for (int off = 1; off < 1024; off <<= 1) {
        int v = (tid >= off) ? sh[tid - off] : 0;
        __syncthreads();
        sh[tid] += v;
        __syncthreads();
    }
    if (tid < 1000) {
        int run = t * E + sh[tid] - sum;
        int* op = offs + t * N + tid * 20;
#pragma unroll
        for (int i = 0; i < 20; i++) { op[i] = run; run += local[i]; }
    }
    if (t == T - 1 && tid == 0) offs[T * N] = T * E;
}

// K2c: per-node running prefix over the 32 blocks -> base_g.
__global__ __launch_bounds__(256) void k_base(
    const unsigned int* __restrict__ hist_g, const int* __restrict__ offs,
    unsigned int* __restrict__ base_g) {
    int node = blockIdx.x * 256 + threadIdx.x;
    if (node >= T * N) return;
    int t = node / N, n = node - t * N;
    const unsigned short* h16 = (const unsigned short*)hist_g;
    int run = offs[node];
#pragma unroll
    for (int b = 0; b < NBA; b++) {
        size_t o = (size_t)(t * NBA + b) * N + n;
        base_g[o] = (unsigned int)run;
        run += h16[o];
    }
}

// K2d: xh[t][n][k] = half(dinv[t][n] * x[t][n][k]). per-t slice 2.56 MB.
__global__ __launch_bounds__(256) void k_cvt(const float* __restrict__ x,
                                             const float* __restrict__ dinv,
                                             __half* __restrict__ xh) {
    int idx = blockIdx.x * 256 + threadIdx.x;   // one float4 per thread
    if (idx >= T * N * 16) return;
    float d = dinv[idx >> 4];
    float4 vv = ((const float4*)x)[idx];
    __half h0 = __float2half(vv.x * d);
    __half h1 = __float2half(vv.y * d);
    __half h2 = __float2half(vv.z * d);
    __half h3 = __float2half(vv.w * d);
    ushort4 pack;
    pack.x = *(unsigned short*)&h0;
    pack.y = *(unsigned short*)&h1;
    pack.z = *(unsigned short*)&h2;
    pack.w = *(unsigned short*)&h3;
    ((ushort4*)xh)[idx] = pack;
}

// K3: fill, agg items only (halves the scattered 4B store count — each
// scattered store costs ~a full HBM line regardless of placement; measured
// R13/R14). P1: place eidx via packed-u16 LDS cursors. P2/P3: accumulate
// the w-sum IN LDS (wacc[src] += dinv[dst], two 10000-key halves to stay
// in 40 KB) and write dense per-block partials coalesced.
__global__ __launch_bounds__(1024) void k_fill(const int* __restrict__ edges,
                                               const unsigned int* __restrict__ base_g,
                                               const float* __restrict__ dinv,
                                               int* __restrict__ eidx,
                                               float* __restrict__ wpart) {
    __shared__ unsigned int arr[NPACK];     // 40 KB, reused across phases
    const int t = blockIdx.x & 7, b = blockIdx.x >> 3;
    const int tid = threadIdx.x;
    const int* keys = edges + (size_t)t * 2 * E + E + b * CHUNKA;   // dst
    const int* pays = edges + (size_t)t * 2 * E + b * CHUNKA;       // src
    const unsigned int* base = base_g + (size_t)(t * NBA + b) * N;
    const float* dv = dinv + t * N;

    // P1: eidx placement
    for (int i = tid; i < NPACK; i += 1024) arr[i] = 0;
    __syncthreads();
    for (int i = tid; i < CHUNKA; i += 1024) {
        int k = keys[i];
        int p = pays[i];
        unsigned int sh = (unsigned int)((k & 1) * 16);
        unsigned int old = atomicAdd(&arr[k >> 1], 1u << sh);
        unsigned int cnt = (old >> sh) & 0xffffu;
        eidx[base[k] + cnt] = p << 6;
    }
    __syncthreads();

    // P2/P3: w-sum partials, one key half at a time
    float* wf = (float*)arr;
    for (int half = 0; half < 2; half++) {
        for (int i = tid; i < NPACK; i += 1024) arr[i] = 0;
        __syncthreads();
        int lo = half * NPACK;
        for (int i = tid; i < CHUNKA; i += 1024) {
            int k = keys[i];
            int q = pays[i] - lo;
            if (q >= 0 && q < NPACK) atomicAdd(&wf[q], dv[k]);
        }
        __syncthreads();
        float* out = wpart + (size_t)(t * NBA + b) * N + lo;
        for (int i = tid; i < NPACK; i += 1024) out[i] = wf[i];
        __syncthreads();
    }
}

// K3b: alpha[t][n] = dinv*(sum_b wpart + dinv). Coalesced 32-way reduce.
__global__ __launch_bounds__(256) void k_wred(const float* __restrict__ wpart,
                                              const float* __restrict__ dinv,
                                              float* __restrict__ alpha) {
    int node = blockIdx.x * 256 + threadIdx.x;
    if (node >= T * N) return;
    int t = node / N, n = node - t * N;
    float s = 0.f;
#pragma unroll
    for (int b = 0; b < NBA; b++) s += wpart[(size_t)(t * NBA + b) * N + n];
    float di = dinv[node];
    alpha[node] = di * (s + di);
}

// K4: gather — one wave per node, lane = feature. Item list loaded once per
// 64 items (coalesced); per-edge indices via __shfl; unroll 8 keeps 8 row
// loads in flight. Emits fp16 operand vh. (alpha handled by k_wred.)
__global__ __launch_bounds__(256) void k_gather(
    const int* __restrict__ eidx, const int* __restrict__ offs,
    const float* __restrict__ dinv, const __half* __restrict__ xh,
    __half* __restrict__ vh) {
    const int t = blockIdx.x & 7;
    const int n = ((blockIdx.x >> 3) << 2) + (threadIdx.x >> 6);
    const int lane = threadIdx.x & 63;
    if (n >= N) return;
    const int node = t * N + n;
    const int start = offs[node];
    const int end = offs[node + 1];
    const __half* xt = xh + (size_t)t * N * 64;
    float acc = 0.f;
    for (int bs = start; bs < end; bs += 64) {
        int cnt = end - bs; if (cnt > 64) cnt = 64;
        int idx = 0;
        if (lane < cnt) idx = __builtin_nontemporal_load(&eidx[bs + lane]);
        int e = 0;
        for (; e + 7 < cnt; e += 8) {
            int o0 = __shfl(idx, e + 0), o1 = __shfl(idx, e + 1);
            int o2 = __shfl(idx, e + 2), o3 = __shfl(idx, e + 3);
            int o4 = __shfl(idx, e + 4), o5 = __shfl(idx, e + 5);
            int o6 = __shfl(idx, e + 6), o7 = __shfl(idx, e + 7);
            float x0 = __half2float(xt[o0 + lane]);
            float x1 = __half2float(xt[o1 + lane]);
            float x2 = __half2float(xt[o2 + lane]);
            float x3 = __half2float(xt[o3 + lane]);
            float x4 = __half2float(xt[o4 + lane]);
            float x5 = __half2float(xt[o5 + lane]);
            float x6 = __half2float(xt[o6 + lane]);
            float x7 = __half2float(xt[o7 + lane]);
            acc += ((x0 + x1) + (x2 + x3)) + ((x4 + x5) + (x6 + x7));
        }
        for (; e < cnt; e++) {
            int o = __shfl(idx, e);
            acc += __half2float(xt[o + lane]);
        }
    }
    float di = dinv[node];
    vh[(size_t)node * 64 + lane] =
        __float2half(di * (acc + __half2float(xt[(n << 6) + lane])));
}

// K5: MFMA layer-1 GEMM (fp16 in, fp32 acc) + BN/ReLU + alpha-pool.
__global__ __launch_bounds__(256) void k_mfma_pool(
    const __half* __restrict__ vh, const float* __restrict__ alpha,
    const __half* __restrict__ W1t,
    const float* __restrict__ b1, const float* __restrict__ g1,
    const float* __restrict__ be1, const float* __restrict__ m1,
    const float* __restrict__ v1, float* __restrict__ pooled) {
    const int t = blockIdx.x & 7;
    const int bt = blockIdx.x >> 3;
    const int w = threadIdx.x >> 6, lane = threadIdx.x & 63;
    const int q = lane >> 4, col = lane & 15;
    const size_t tb = (size_t)t * N;

    f16x8 bfr[8][2];
    float sbv[8], stv[8];
#pragma unroll
    for (int jt = 0; jt < 8; jt++) {
        int j = jt * 16 + col;
        float s = g1[j] * rsqrtf(v1[j] + EPS);
        sbv[jt] = s;
        stv[jt] = s * b1[j] + be1[j] - m1[j] * s;
#pragma unroll
        for (int kk = 0; kk < 2; kk++)
            bfr[jt][kk] = *(const f16x8*)(W1t + (size_t)j * 64 + kk * 32 + q * 8);
    }
    float pool8[8];
#pragma unroll
    for (int jt = 0; jt < 8; jt++) pool8[jt] = 0.f;

    for (int i = 0; i < 8; i++) {
        int tau = bt * 32 + w * 8 + i;
        if (tau >= TILES_PT) break;
        int nb = tau * 16;
        const __half* vrow = vh + (tb + nb + col) * 64;
        f16x8 a0 = *(const f16x8*)(vrow + q * 8);
        f16x8 a1 = *(const f16x8*)(vrow + 32 + q * 8);
        float4 af = ((const float4*)(alpha + tb + nb))[q];
#pragma unroll
        for (int jt = 0; jt < 8; jt++) {
            f32x4 acc = {0.f, 0.f, 0.f, 0.f};
            acc = __builtin_amdgcn_mfma_f32_16x16x32_f16(a0, bfr[jt][0], acc, 0, 0, 0);
            acc = __builtin_amdgcn_mfma_f32_16x16x32_f16(a1, bfr[jt][1], acc, 0, 0, 0);
            float s = sbv[jt], sh = stv[jt];
            pool8[jt] += fmaxf(s * acc[0] + sh, 0.f) * af.x
                       + fmaxf(s * acc[1] + sh, 0.f) * af.y
                       + fmaxf(s * acc[2] + sh, 0.f) * af.z
                       + fmaxf(s * acc[3] + sh, 0.f) * af.w;
        }
    }
#pragma unroll
    for (int jt = 0; jt < 8; jt++) {
        pool8[jt] += __shfl_xor(pool8[jt], 16);
        pool8[jt] += __shfl_xor(pool8[jt], 32);
    }
    if (lane < 16) {
#pragma unroll
        for (int jt = 0; jt < 8; jt++)
            atomicAdd(&pooled[t * 128 + jt * 16 + lane], pool8[jt]);
    }
}

// K6a: warm every XCD's L2 with the recurrence weights (768 KB).
__global__ __launch_bounds__(256) void k_warm(const float* __restrict__ a,
                                              const float* __restrict__ b,
                                              const float* __restrict__ c,
                                              float* __restrict__ sink) {
    int slice = blockIdx.x >> 3;           // 0..7, 24576 floats each
    int start = slice * 24576;
    float s = 0.f;
    for (int i = start + threadIdx.x; i < start + 24576; i += 256) {
        float v;
        if (i < 65536) v = a[i];
        else if (i < 131072) v = b[i - 65536];
        else v = c[i - 131072];
        s += v;
    }
    sink[blockIdx.x * 256 + threadIdx.x] = s;
}

// K6b: emb = bn2(pooled/N @ W2 + b2) and layer-0 x-part gates.
__global__ __launch_bounds__(512) void k_emb(
    const float* __restrict__ pooled,
    const float* __restrict__ W2, const float* __restrict__ b2,
    const float* __restrict__ g2, const float* __restrict__ be2,
    const float* __restrict__ m2, const float* __restrict__ v2,
    const float* __restrict__ Wih0, const float* __restrict__ bih0,
    const float* __restrict__ bhh0, float* __restrict__ gx0_g) {
    const int t = blockIdx.x, tid = threadIdx.x;
    __shared__ float pm[128];
    __shared__ float es[128];
    if (tid < 128) pm[tid] = pooled[t * 128 + tid] * (1.0f / N);
    __syncthreads();
    if (tid < 128) {
        float s = g2[tid] * rsqrtf(v2[tid] + EPS);
        float sh = be2[tid] - m2[tid] * s;
        float dot = 0.f;
#pragma unroll 8
        for (int k = 0; k < 128; k++) dot += pm[k] * W2[k * 128 + tid];
        es[tid] = s * (dot + b2[tid]) + sh;
    }
    __syncthreads();
    float dot = bih0[tid] + bhh0[tid];
    const float4* w = (const float4*)(Wih0 + tid * 128);
    const float4* e4 = (const float4*)es;
#pragma unroll
    for (int k4 = 0; k4 < 32; k4++) {
        float4 a = w[k4], bb = e4[k4];
        dot += a.x * bb.x + a.y * bb.y + a.z * bb.z + a.w * bb.w;
    }
    gx0_g[t * 512 + tid] = dot;
}

// K6c: single block, 1024 threads. Thread (r = tid&511, hf = tid>>9) owns a
// HALF gate row (16 float4 = 64 VGPRs). Halves combine through LDS part[].
__global__ __launch_bounds__(1024, 4) void k_head(
    const float* __restrict__ gx0_g,
    const float* __restrict__ Whh0, const float* __restrict__ Whh1,
    const float* __restrict__ Wih1, const float* __restrict__ bih1,
    const float* __restrict__ bhh1,
    const float* __restrict__ Wc, const float* __restrict__ bc,
    float* __restrict__ out) {
    __shared__ float gx0[T][512];
    __shared__ float gx1h[2][T][512];
    __shared__ float ys[T][128];
    __shared__ float h[128];
    __shared__ float part[1024];
    const int tid = threadIdx.x;
    const int r = tid & 511, hf = tid >> 9;

    for (int i = tid; i < T * 512; i += 1024) gx0[i >> 9][i & 511] = gx0_g[i];
    if (tid < 128) h[tid] = 0.f;

    float4 w[16];
    {
        const float4* p = (const float4*)(Whh0 + r * 128 + hf * 64);
#pragma unroll
        for (int k = 0; k < 16; k++) w[k] = p[k];
    }
    float c = 0.f;
    __syncthreads();

    // LSTM layer 0
    for (int t = 0; t < T; t++) {
        const float4* h4 = ((const float4*)h) + hf * 16;
        float dot = 0.f;
#pragma unroll
        for (int k = 0; k < 16; k++) {
            float4 hv = h4[k];
            dot += w[k].x * hv.x + w[k].y * hv.y + w[k].z * hv.z + w[k].w * hv.w;
        }
        part[tid] = dot;
        __syncthreads();
        if (tid < 128) {
            float i_ = gx0[t][tid]       + part[tid]       + part[512 + tid];
            float f_ = gx0[t][128 + tid] + part[128 + tid] + part[640 + tid];
            float g_ = gx0[t][256 + tid] + part[256 + tid] + part[768 + tid];
            float o_ = gx0[t][384 + tid] + part[384 + tid] + part[896 + tid];
            c = sigm(f_) * c + sigm(i_) * tanhf(g_);
            float hv = sigm(o_) * tanhf(c);
            h[tid] = hv;
            ys[t][tid] = hv;
        }
        __syncthreads();
    }

    // gx1 halves
    {
        const float4* p = (const float4*)(Wih1 + r * 128 + hf * 64);
#pragma unroll
        for (int k = 0; k < 16; k++) w[k] = p[k];
        float bias = (hf == 0) ? (bih1[r] + bhh1[r]) : 0.f;
        for (int t = 0; t < T; t++) {
            const float4* y4 = ((const float4*)ys[t]) + hf * 16;
            float dot = bias;
#pragma unroll
            for (int k = 0; k < 16; k++) {
                float4 yv = y4[k];
                dot += w[k].x * yv.x + w[k].y * yv.y + w[k].z * yv.z + w[k].w * yv.w;
            }
            gx1h[hf][t][r] = dot;
        }
    }

    // LSTM layer 1
    {
        const float4* p = (const float4*)(Whh1 + r * 128 + hf * 64);
#pragma unroll
        for (int k = 0; k < 16; k++) w[k] = p[k];
    }
    if (tid < 128) h[tid] = 0.f;
    c = 0.f;
    __syncthreads();
    for (int t = 0; t < T; t++) {
        const float4* h4 = ((const float4*)h) + hf * 16;
        float dot = 0.f;
#pragma unroll
        for (int k = 0; k < 16; k++) {
            float4 hv = h4[k];
            dot += w[k].x * hv.x + w[k].y * hv.y + w[k].z * hv.z + w[k].w * hv.w;
        }
        part[tid] = dot;
        __syncthreads();
        if (tid < 128) {
            float i_ = gx1h[0][t][tid]       + gx1h[1][t][tid]       + part[tid]       + part[512 + tid];
            float f_ = gx1h[0][t][128 + tid] + gx1h[1][t][128 + tid] + part[128 + tid] + part[640 + tid];
            float g_ = gx1h[0][t][256 + tid] + gx1h[1][t][256 + tid] + part[256 + tid] + part[768 + tid];
            float o_ = gx1h[0][t][384 + tid] + gx1h[1][t][384 + tid] + part[384 + tid] + part[896 + tid];
            c = sigm(f_) * c + sigm(i_) * tanhf(g_);
            h[tid] = sigm(o_) * tanhf(c);
        }
        __syncthreads();
    }

    if (tid < 2) {
        float dot = bc[tid];
#pragma unroll 8
        for (int k = 0; k < 128; k++) dot += h[k] * Wc[tid * 128 + k];
        out[tid] = dot;
    }
    if (tid < 128) out[2 + tid] = h[tid];
}

// ---------------------------------------------------------------------------
extern "C" void kernel_launch(void* const* d_in, const int* in_sizes, int n_in,
                              void* d_out, int out_size, void* d_ws, size_t ws_size,
                              hipStream_t stream) {
    const float* x    = (const float*)d_in[0];
    const int*   edges= (const int*)d_in[1];
    const float* W1   = (const float*)d_in[2];
    const float* b1   = (const float*)d_in[3];
    const float* g1   = (const float*)d_in[4];
    const float* be1  = (const float*)d_in[5];
    const float* m1   = (const float*)d_in[6];
    const float* v1   = (const float*)d_in[7];
    const float* W2   = (const float*)d_in[8];
    const float* b2   = (const float*)d_in[9];
    const float* g2   = (const float*)d_in[10];
    const float* be2  = (const float*)d_in[11];
    const float* m2   = (const float*)d_in[12];
    const float* v2   = (const float*)d_in[13];
    const float* Wih0 = (const float*)d_in[14];
    const float* Whh0 = (const float*)d_in[15];
    const float* bih0 = (const float*)d_in[16];
    const float* bhh0 = (const float*)d_in[17];
    const float* Wih1 = (const float*)d_in[18];
    const float* Whh1 = (const float*)d_in[19];
    const float* bih1 = (const float*)d_in[20];
    const float* bhh1 = (const float*)d_in[21];
    const float* Wc   = (const float*)d_in[22];
    const float* bc   = (const float*)d_in[23];

    char* base = (char*)d_ws;
    // Aliasing: hist_g (10.24 MB) + base_g (20.48 MB) occupy [0, 30.72 MB).
    // vh (20.5 MB) aliases that region — hist_g dead after k_base, base_g
    // dead after k_fill, vh written in k_gather (after k_fill). Safe.
    unsigned int* hist_g = (unsigned int*)base;                       // T*NBA*NPACK u32
    unsigned int* base_g = (unsigned int*)(base + (size_t)T * NBA * NPACK * 4);
    __half*       vh     = (__half*)base;                             // T*N*64 f16
    char* p = base + (size_t)T * NBA * NPACK * 4 + (size_t)T * NBA * N * 4;
    __half* xh   = (__half*)p;              p += (size_t)T * N * 64 * 2;  // 20.5 MB
    int*   offs  = (int*)p;                 p += (size_t)(T * N + 1) * 4 + 12; // keep 16B align
    int*   dega  = (int*)p;                 p += (size_t)T * N * 4;
    float* dinv  = (float*)p;               p += (size_t)T * N * 4;
    float* alpha = (float*)p;               p += (size_t)T * N * 4;
    int*   tot   = (int*)p;                 p += (size_t)T * N * 4;   // warm sink
    int*   eidx  = (int*)p;                 p += (size_t)T * E * 4;   // 10.25 MB
    float* wpart = (float*)p;               p += (size_t)T * NBA * N * 4; // 20.5 MB
    float* pooled= (float*)p;               p += (size_t)T * 128 * 4;
    float* gx0_g = (float*)p;               p += (size_t)T * 512 * 4;
    __half* W1t  = (__half*)p;

    (void)hipMemsetAsync(pooled, 0, T * 128 * sizeof(float), stream);

    k_prepw<<<32, 256, 0, stream>>>(W1, W1t);
    dim3 gs(T, NBA);
    k_hist<<<gs, 1024, 0, stream>>>(edges, hist_g);
    k_colsum<<<(T * NPACK + 255) / 256, 256, 0, stream>>>(hist_g, dega, dinv);
    k_scanN<<<T, 1024, 0, stream>>>(dega, offs);
    k_base<<<(T * N + 255) / 256, 256, 0, stream>>>(hist_g, offs, base_g);
    k_cvt<<<(T * N * 16 + 255) / 256, 256, 0, stream>>>(x, dinv, xh);
    k_fill<<<T * NBA, 1024, 0, stream>>>(edges, base_g, dinv, eidx, wpart);
    k_wred<<<(T * N + 255) / 256, 256, 0, stream>>>(wpart, dinv, alpha);
    k_gather<<<(T * N) / 4, 256, 0, stream>>>(eidx, offs, dinv, xh, vh);
    k_mfma_pool<<<8 * 40, 256, 0, stream>>>(vh, alpha, W1t, b1, g1, be1, m1, v1, pooled);

    k_warm<<<64, 256, 0, stream>>>(Whh0, Whh1, Wih1, (float*)tot);
    k_emb<<<T, 512, 0, stream>>>(pooled, W2, b2, g2, be2, m2, v2, Wih0, bih0, bhh0, gx0_g);
    k_head<<<1, 1024, 0, stream>>>(gx0_g, Whh0, Whh1, Wih1, bih1, bhh1, Wc, bc, (float*)d_out);
}

// Round 16
// 402.830 us; speedup vs baseline: 1.4129x; 1.0518x over previous
//
#include <hip/hip_runtime.h>
#include <hip/hip_fp16.h>
#include <math.h>

#define T 8
#define N 20000
#define E 320000
#define EPS 1e-5f
#define NBA 32         // agg-item sort blocks per t
#define CHUNKA 10000   // E/32 items per block
#define NPACK 10000    // N/2 packed u32 (2 x u16 counters)
#define TILES_PT 1250  // 16-node MFMA tiles per t
#define BW 625         // nodes per dst-bucket
#define NBUK 32        // dst-buckets per t
#define SPAN_MAX 13824 // LDS stage cap (mean span 10000, sigma ~100)

typedef _Float16 f16x8 __attribute__((ext_vector_type(8)));
typedef float f32x4 __attribute__((ext_vector_type(4)));

__device__ __forceinline__ float sigm(float x) { return 1.0f / (1.0f + expf(-x)); }

// ---------------------------------------------------------------------------
// K0: W1t[j][k] = half(W1[k][j])  (fp16 transposed weights for MFMA B-frags)
__global__ __launch_bounds__(256) void k_prepw(const float* __restrict__ W1,
                                               __half* __restrict__ W1t) {
    int i = blockIdx.x * 256 + threadIdx.x;
    if (i >= 64 * 128) return;
    int j = i & 127, k = i >> 7;
    W1t[j * 64 + k] = __float2half(W1[i]);
}

// K1: per-(t,block) LDS histogram of agg-item keys (dst) -> per-node degrees.
__global__ __launch_bounds__(1024) void k_hist(const int* __restrict__ edges,
                                               unsigned int* __restrict__ hist_g) {
    __shared__ unsigned int h32[NPACK];
    const int t = blockIdx.x, b = blockIdx.y;
    const int tid = threadIdx.x;
    for (int i = tid; i < NPACK; i += 1024) h32[i] = 0;
    __syncthreads();
    const int* keys = edges + (size_t)t * 2 * E + E + b * CHUNKA;   // dst half
    for (int i = tid; i < CHUNKA; i += 1024) {
        int k = keys[i];
        atomicAdd(&h32[k >> 1], 1u << ((k & 1) * 16));
    }
    __syncthreads();
    unsigned int* out = hist_g + (size_t)(t * NBA + b) * NPACK;
    for (int i = tid; i < NPACK; i += 1024) out[i] = h32[i];
}

// K2a: column sum over the 32 agg blocks — dega = in-degree; dinv.
__global__ __launch_bounds__(256) void k_colsum(
    const unsigned int* __restrict__ hist_g,
    int* __restrict__ dega, float* __restrict__ dinv) {
    int idx = blockIdx.x * 256 + threadIdx.x;
    if (idx >= T * NPACK) return;
    int t = idx / NPACK, i = idx - t * NPACK;
    const unsigned int* hp = hist_g + (size_t)t * NBA * NPACK + i;
    unsigned int a0 = 0, a1 = 0;
#pragma unroll
    for (int b = 0; b < NBA; b++) {
        unsigned int h = hp[(size_t)b * NPACK];
        a0 += h & 0xffffu; a1 += h >> 16;
    }
    int n0 = t * N + 2 * i;
    dega[n0]     = (int)a0;
    dega[n0 + 1] = (int)a1;
    dinv[n0]     = rsqrtf((float)a0 + 1.0f);
    dinv[n0 + 1] = rsqrtf((float)a1 + 1.0f);
}

// K2b: per-t exclusive prefix over node in-degrees -> offs (+ sentinel).
__global__ __launch_bounds__(1024) void k_scanN(const int* __restrict__ dega,
                                                int* __restrict__ offs) {
    const int t = blockIdx.x, tid = threadIdx.x;
    __shared__ int sh[1024];
    int local[20];
    int sum = 0;
    if (tid < 1000) {
        const int* tp = dega + t * N + tid * 20;
#pragma unroll
        for (int i = 0; i < 20; i++) { local[i] = tp[i]; sum += local[i]; }
    }
    sh[tid] = sum;
    __syncthreads();
    for (int off = 1; off < 1024; off <<= 1) {
        int v = (tid >= off) ? sh[tid - off] : 0;
        __syncthreads();
        sh[tid] += v;
        __syncthreads();
    }
    if (tid < 1000) {
        int run = t * E + sh[tid] - sum;
        int* op = offs + t * N + tid * 20;
#pragma unroll
        for (int i = 0; i < 20; i++) { op[i] = run; run += local[i]; }
    }
    if (t == T - 1 && tid == 0) offs[T * N] = T * E;
}

// K2d: xh[t][n][k] = half(dinv[t][n] * x[t][n][k]). per-t slice 2.56 MB.
__global__ __launch_bounds__(256) void k_cvt(const float* __restrict__ x,
                                             const float* __restrict__ dinv,
                                             __half* __restrict__ xh) {
    int idx = blockIdx.x * 256 + threadIdx.x;   // one float4 per thread
    if (idx >= T * N * 16) return;
    float d = dinv[idx >> 4];
    float4 vv = ((const float4*)x)[idx];
    __half h0 = __float2half(vv.x * d);
    __half h1 = __float2half(vv.y * d);
    __half h2 = __float2half(vv.z * d);
    __half h3 = __float2half(vv.w * d);
    ushort4 pack;
    pack.x = *(unsigned short*)&h0;
    pack.y = *(unsigned short*)&h1;
    pack.z = *(unsigned short*)&h2;
    pack.w = *(unsigned short*)&h3;
    ((ushort4*)xh)[idx] = pack;
}

// K3a: partition pass. Each (t,b) bins its 10000 items into 32 dst-buckets
// in LDS, writes the bucket-ordered run COALESCED to bpart, plus per-bucket
// counts. Then the w-sum LDS phases (unchanged from R15). Zero scattered
// global stores.
__global__ __launch_bounds__(1024) void k_part(const int* __restrict__ edges,
                                               const float* __restrict__ dinv,
                                               unsigned int* __restrict__ bpart,
                                               int* __restrict__ bcnt,
                                               float* __restrict__ wpart) {
    __shared__ unsigned int stage[CHUNKA];   // 40 KB, reused across phases
    __shared__ int cnt[NBUK], cur[NBUK];
    const int t = blockIdx.x & 7, b = blockIdx.x >> 3;
    const int tid = threadIdx.x;
    const int* keys = edges + (size_t)t * 2 * E + E + b * CHUNKA;   // dst
    const int* pays = edges + (size_t)t * 2 * E + b * CHUNKA;       // src
    if (tid < NBUK) cnt[tid] = 0;
    __syncthreads();
    for (int i = tid; i < CHUNKA; i += 1024)
        atomicAdd(&cnt[keys[i] / BW], 1);
    __syncthreads();
    if (tid == 0) {
        int run = 0;
        for (int u = 0; u < NBUK; u++) { cur[u] = run; run += cnt[u]; }
    }
    __syncthreads();
    for (int i = tid; i < CHUNKA; i += 1024) {
        int k = keys[i];
        int p = pays[i];
        int u = k / BW;
        int slot = atomicAdd(&cur[u], 1);
        stage[slot] = ((unsigned int)(k - u * BW) << 15) | (unsigned int)p;
    }
    __syncthreads();
    unsigned int* outp = bpart + (size_t)(t * NBUK + b) * CHUNKA;
    for (int i = tid; i < CHUNKA; i += 1024) outp[i] = stage[i];
    if (tid < NBUK) bcnt[(t * NBUK + tid) * NBUK + b] = cnt[tid];
    __syncthreads();

    // w-sum partials (reuse stage as float wacc), two key halves
    float* wf = (float*)stage;
    const float* dv = dinv + t * N;
    for (int half = 0; half < 2; half++) {
        for (int i = tid; i < NPACK; i += 1024) wf[i] = 0.f;
        __syncthreads();
        int lo = half * NPACK;
        for (int i = tid; i < CHUNKA; i += 1024) {
            int k = keys[i];
            int q = pays[i] - lo;
            if (q >= 0 && q < NPACK) atomicAdd(&wf[q], dv[k]);
        }
        __syncthreads();
        float* out = wpart + (size_t)(t * NBUK + b) * N + lo;
        for (int i = tid; i < NPACK; i += 1024) out[i] = wf[i];
        __syncthreads();
    }
}

// K3b: placement pass. One block per (t,bucket): gathers the bucket's items
// from the 32 per-block runs (coalesced reads), resolves CSR positions via
// 625 LDS cursors, stages the segment in LDS, writes it out as FULL LINES.
__global__ __launch_bounds__(1024) void k_place(const unsigned int* __restrict__ bpart,
                                                const int* __restrict__ bcnt,
                                                const int* __restrict__ offs,
                                                int* __restrict__ eidx) {
    __shared__ int stage[SPAN_MAX];          // 54 KB
    __shared__ int cursor[BW];
    __shared__ int offb[NBUK], lenb[NBUK];
    const int t = blockIdx.x & 7, u = blockIdx.x >> 3;
    const int tid = threadIdx.x;
    const int nodeBase = t * N + u * BW;
    const int segStart = offs[nodeBase];
    const int segEnd = offs[nodeBase + BW];
    const int span = segEnd - segStart;
    if (tid < NBUK) {
        int s = 0;
        for (int uu = 0; uu < u; uu++) s += bcnt[(t * NBUK + uu) * NBUK + tid];
        offb[tid] = s;
        lenb[tid] = bcnt[(t * NBUK + u) * NBUK + tid];
    }
    for (int j = tid; j < BW; j += 1024) cursor[j] = offs[nodeBase + j] - segStart;
    __syncthreads();
    if (span <= SPAN_MAX) {
        for (int b = 0; b < NBUK; b++) {
            const unsigned int* src = bpart + (size_t)(t * NBUK + b) * CHUNKA + offb[b];
            int len = lenb[b];
            for (int i = tid; i < len; i += 1024) {
                unsigned int it = src[i];
                int pos = atomicAdd(&cursor[it >> 15], 1);
                stage[pos] = (int)(it & 0x7fffu) << 6;
            }
            __syncthreads();
        }
        int* out = eidx + segStart;
        for (int i = tid; i < span; i += 1024) out[i] = stage[i];
    } else {                                  // statistically unreachable fallback
        for (int b = 0; b < NBUK; b++) {
            const unsigned int* src = bpart + (size_t)(t * NBUK + b) * CHUNKA + offb[b];
            int len = lenb[b];
            for (int i = tid; i < len; i += 1024) {
                unsigned int it = src[i];
                int pos = atomicAdd(&cursor[it >> 15], 1);
                eidx[segStart + pos] = (int)(it & 0x7fffu) << 6;
            }
            __syncthreads();
        }
    }
}

// K3c: alpha[t][n] = dinv*(sum_b wpart + dinv). Coalesced 32-way reduce.
__global__ __launch_bounds__(256) void k_wred(const float* __restrict__ wpart,
                                              const float* __restrict__ dinv,
                                              float* __restrict__ alpha) {
    int node = blockIdx.x * 256 + threadIdx.x;
    if (node >= T * N) return;
    int t = node / N, n = node - t * N;
    float s = 0.f;
#pragma unroll
    for (int b = 0; b < NBUK; b++) s += wpart[(size_t)(t * NBUK + b) * N + n];
    float di = dinv[node];
    alpha[node] = di * (s + di);
}

// K4: gather — one wave per node, lane = feature. Item list loaded once per
// 64 items (coalesced); per-edge indices via __shfl; unroll 8 keeps 8 row
// loads in flight. Emits fp16 operand vh.
__global__ __launch_bounds__(256) void k_gather(
    const int* __restrict__ eidx, const int* __restrict__ offs,
    const float* __restrict__ dinv, const __half* __restrict__ xh,
    __half* __restrict__ vh) {
    const int t = blockIdx.x & 7;
    const int n = ((blockIdx.x >> 3) << 2) + (threadIdx.x >> 6);
    const int lane = threadIdx.x & 63;
    if (n >= N) return;
    const int node = t * N + n;
    const int start = offs[node];
    const int end = offs[node + 1];
    const __half* xt = xh + (size_t)t * N * 64;
    float acc = 0.f;
    for (int bs = start; bs < end; bs += 64) {
        int cnt = end - bs; if (cnt > 64) cnt = 64;
        int idx = 0;
        if (lane < cnt) idx = __builtin_nontemporal_load(&eidx[bs + lane]);
        int e = 0;
        for (; e + 7 < cnt; e += 8) {
            int o0 = __shfl(idx, e + 0), o1 = __shfl(idx, e + 1);
            int o2 = __shfl(idx, e + 2), o3 = __shfl(idx, e + 3);
            int o4 = __shfl(idx, e + 4), o5 = __shfl(idx, e + 5);
            int o6 = __shfl(idx, e + 6), o7 = __shfl(idx, e + 7);
            float x0 = __half2float(xt[o0 + lane]);
            float x1 = __half2float(xt[o1 + lane]);
            float x2 = __half2float(xt[o2 + lane]);
            float x3 = __half2float(xt[o3 + lane]);
            float x4 = __half2float(xt[o4 + lane]);
            float x5 = __half2float(xt[o5 + lane]);
            float x6 = __half2float(xt[o6 + lane]);
            float x7 = __half2float(xt[o7 + lane]);
            acc += ((x0 + x1) + (x2 + x3)) + ((x4 + x5) + (x6 + x7));
        }
        for (; e < cnt; e++) {
            int o = __shfl(idx, e);
            acc += __half2float(xt[o + lane]);
        }
    }
    float di = dinv[node];
    vh[(size_t)node * 64 + lane] =
        __float2half(di * (acc + __half2float(xt[(n << 6) + lane])));
}

// K5: MFMA layer-1 GEMM (fp16 in, fp32 acc) + BN/ReLU + alpha-pool.
__global__ __launch_bounds__(256) void k_mfma_pool(
    const __half* __restrict__ vh, const float* __restrict__ alpha,
    const __half* __restrict__ W1t,
    const float* __restrict__ b1, const float* __restrict__ g1,
    const float* __restrict__ be1, const float* __restrict__ m1,
    const float* __restrict__ v1, float* __restrict__ pooled) {
    const int t = blockIdx.x & 7;
    const int bt = blockIdx.x >> 3;
    const int w = threadIdx.x >> 6, lane = threadIdx.x & 63;
    const int q = lane >> 4, col = lane & 15;
    const size_t tb = (size_t)t * N;

    f16x8 bfr[8][2];
    float sbv[8], stv[8];
#pragma unroll
    for (int jt = 0; jt < 8; jt++) {
        int j = jt * 16 + col;
        float s = g1[j] * rsqrtf(v1[j] + EPS);
        sbv[jt] = s;
        stv[jt] = s * b1[j] + be1[j] - m1[j] * s;
#pragma unroll
        for (int kk = 0; kk < 2; kk++)
            bfr[jt][kk] = *(const f16x8*)(W1t + (size_t)j * 64 + kk * 32 + q * 8);
    }
    float pool8[8];
#pragma unroll
    for (int jt = 0; jt < 8; jt++) pool8[jt] = 0.f;

    for (int i = 0; i < 8; i++) {
        int tau = bt * 32 + w * 8 + i;
        if (tau >= TILES_PT) break;
        int nb = tau * 16;
        const __half* vrow = vh + (tb + nb + col) * 64;
        f16x8 a0 = *(const f16x8*)(vrow + q * 8);
        f16x8 a1 = *(const f16x8*)(vrow + 32 + q * 8);
        float4 af = ((const float4*)(alpha + tb + nb))[q];
#pragma unroll
        for (int jt = 0; jt < 8; jt++) {
            f32x4 acc = {0.f, 0.f, 0.f, 0.f};
            acc = __builtin_amdgcn_mfma_f32_16x16x32_f16(a0, bfr[jt][0], acc, 0, 0, 0);
            acc = __builtin_amdgcn_mfma_f32_16x16x32_f16(a1, bfr[jt][1], acc, 0, 0, 0);
            float s = sbv[jt], sh = stv[jt];
            pool8[jt] += fmaxf(s * acc[0] + sh, 0.f) * af.x
                       + fmaxf(s * acc[1] + sh, 0.f) * af.y
                       + fmaxf(s * acc[2] + sh, 0.f) * af.z
                       + fmaxf(s * acc[3] + sh, 0.f) * af.w;
        }
    }
#pragma unroll
    for (int jt = 0; jt < 8; jt++) {
        pool8[jt] += __shfl_xor(pool8[jt], 16);
        pool8[jt] += __shfl_xor(pool8[jt], 32);
    }
    if (lane < 16) {
#pragma unroll
        for (int jt = 0; jt < 8; jt++)
            atomicAdd(&pooled[t * 128 + jt * 16 + lane], pool8[jt]);
    }
}

// K6a: warm every XCD's L2 with the recurrence weights (768 KB).
__global__ __launch_bounds__(256) void k_warm(const float* __restrict__ a,
                                              const float* __restrict__ b,
                                              const float* __restrict__ c,
                                              float* __restrict__ sink) {
    int slice = blockIdx.x >> 3;           // 0..7, 24576 floats each
    int start = slice * 24576;
    float s = 0.f;
    for (int i = start + threadIdx.x; i < start + 24576; i += 256) {
        float v;
        if (i < 65536) v = a[i];
        else if (i < 131072) v = b[i - 65536];
        else v = c[i - 131072];
        s += v;
    }
    sink[blockIdx.x * 256 + threadIdx.x] = s;
}

// K6b: emb = bn2(pooled/N @ W2 + b2) and layer-0 x-part gates.
__global__ __launch_bounds__(512) void k_emb(
    const float* __restrict__ pooled,
    const float* __restrict__ W2, const float* __restrict__ b2,
    const float* __restrict__ g2, const float* __restrict__ be2,
    const float* __restrict__ m2, const float* __restrict__ v2,
    const float* __restrict__ Wih0, const float* __restrict__ bih0,
    const float* __restrict__ bhh0, float* __restrict__ gx0_g) {
    const int t = blockIdx.x, tid = threadIdx.x;
    __shared__ float pm[128];
    __shared__ float es[128];
    if (tid < 128) pm[tid] = pooled[t * 128 + tid] * (1.0f / N);
    __syncthreads();
    if (tid < 128) {
        float s = g2[tid] * rsqrtf(v2[tid] + EPS);
        float sh = be2[tid] - m2[tid] * s;
        float dot = 0.f;
#pragma unroll 8
        for (int k = 0; k < 128; k++) dot += pm[k] * W2[k * 128 + tid];
        es[tid] = s * (dot + b2[tid]) + sh;
    }
    __syncthreads();
    float dot = bih0[tid] + bhh0[tid];
    const float4* w = (const float4*)(Wih0 + tid * 128);
    const float4* e4 = (const float4*)es;
#pragma unroll
    for (int k4 = 0; k4 < 32; k4++) {
        float4 a = w[k4], bb = e4[k4];
        dot += a.x * bb.x + a.y * bb.y + a.z * bb.z + a.w * bb.w;
    }
    gx0_g[t * 512 + tid] = dot;
}

// K6c: single block, 1024 threads. Thread (r = tid&511, hf = tid>>9) owns a
// HALF gate row (16 float4 = 64 VGPRs). Halves combine through LDS part[].
__global__ __launch_bounds__(1024, 4) void k_head(
    const float* __restrict__ gx0_g,
    const float* __restrict__ Whh0, const float* __restrict__ Whh1,
    const float* __restrict__ Wih1, const float* __restrict__ bih1,
    const float* __restrict__ bhh1,
    const float* __restrict__ Wc, const float* __restrict__ bc,
    float* __restrict__ out) {
    __shared__ float gx0[T][512];
    __shared__ float gx1h[2][T][512];
    __shared__ float ys[T][128];
    __shared__ float h[128];
    __shared__ float part[1024];
    const int tid = threadIdx.x;
    const int r = tid & 511, hf = tid >> 9;

    for (int i = tid; i < T * 512; i += 1024) gx0[i >> 9][i & 511] = gx0_g[i];
    if (tid < 128) h[tid] = 0.f;

    float4 w[16];
    {
        const float4* p = (const float4*)(Whh0 + r * 128 + hf * 64);
#pragma unroll
        for (int k = 0; k < 16; k++) w[k] = p[k];
    }
    float c = 0.f;
    __syncthreads();

    // LSTM layer 0
    for (int t = 0; t < T; t++) {
        const float4* h4 = ((const float4*)h) + hf * 16;
        float dot = 0.f;
#pragma unroll
        for (int k = 0; k < 16; k++) {
            float4 hv = h4[k];
            dot += w[k].x * hv.x + w[k].y * hv.y + w[k].z * hv.z + w[k].w * hv.w;
        }
        part[tid] = dot;
        __syncthreads();
        if (tid < 128) {
            float i_ = gx0[t][tid]       + part[tid]       + part[512 + tid];
            float f_ = gx0[t][128 + tid] + part[128 + tid] + part[640 + tid];
            float g_ = gx0[t][256 + tid] + part[256 + tid] + part[768 + tid];
            float o_ = gx0[t][384 + tid] + part[384 + tid] + part[896 + tid];
            c = sigm(f_) * c + sigm(i_) * tanhf(g_);
            float hv = sigm(o_) * tanhf(c);
            h[tid] = hv;
            ys[t][tid] = hv;
        }
        __syncthreads();
    }

    // gx1 halves
    {
        const float4* p = (const float4*)(Wih1 + r * 128 + hf * 64);
#pragma unroll
        for (int k = 0; k < 16; k++) w[k] = p[k];
        float bias = (hf == 0) ? (bih1[r] + bhh1[r]) : 0.f;
        for (int t = 0; t < T; t++) {
            const float4* y4 = ((const float4*)ys[t]) + hf * 16;
            float dot = bias;
#pragma unroll
            for (int k = 0; k < 16; k++) {
                float4 yv = y4[k];
                dot += w[k].x * yv.x + w[k].y * yv.y + w[k].z * yv.z + w[k].w * yv.w;
            }
            gx1h[hf][t][r] = dot;
        }
    }

    // LSTM layer 1
    {
        const float4* p = (const float4*)(Whh1 + r * 128 + hf * 64);
#pragma unroll
        for (int k = 0; k < 16; k++) w[k] = p[k];
    }
    if (tid < 128) h[tid] = 0.f;
    c = 0.f;
    __syncthreads();
    for (int t = 0; t < T; t++) {
        const float4* h4 = ((const float4*)h) + hf * 16;
        float dot = 0.f;
#pragma unroll
        for (int k = 0; k < 16; k++) {
            float4 hv = h4[k];
            dot += w[k].x * hv.x + w[k].y * hv.y + w[k].z * hv.z + w[k].w * hv.w;
        }
        part[tid] = dot;
        __syncthreads();
        if (tid < 128) {
            float i_ = gx1h[0][t][tid]       + gx1h[1][t][tid]       + part[tid]       + part[512 + tid];
            float f_ = gx1h[0][t][128 + tid] + gx1h[1][t][128 + tid] + part[128 + tid] + part[640 + tid];
            float g_ = gx1h[0][t][256 + tid] + gx1h[1][t][256 + tid] + part[256 + tid] + part[768 + tid];
            float o_ = gx1h[0][t][384 + tid] + gx1h[1][t][384 + tid] + part[384 + tid] + part[896 + tid];
            c = sigm(f_) * c + sigm(i_) * tanhf(g_);
            h[tid] = sigm(o_) * tanhf(c);
        }
        __syncthreads();
    }

    if (tid < 2) {
        float dot = bc[tid];
#pragma unroll 8
        for (int k = 0; k < 128; k++) dot += h[k] * Wc[tid * 128 + k];
        out[tid] = dot;
    }
    if (tid < 128) out[2 + tid] = h[tid];
}

// ---------------------------------------------------------------------------
extern "C" void kernel_launch(void* const* d_in, const int* in_sizes, int n_in,
                              void* d_out, int out_size, void* d_ws, size_t ws_size,
                              hipStream_t stream) {
    const float* x    = (const float*)d_in[0];
    const int*   edges= (const int*)d_in[1];
    const float* W1   = (const float*)d_in[2];
    const float* b1   = (const float*)d_in[3];
    const float* g1   = (const float*)d_in[4];
    const float* be1  = (const float*)d_in[5];
    const float* m1   = (const float*)d_in[6];
    const float* v1   = (const float*)d_in[7];
    const float* W2   = (const float*)d_in[8];
    const float* b2   = (const float*)d_in[9];
    const float* g2   = (const float*)d_in[10];
    const float* be2  = (const float*)d_in[11];
    const float* m2   = (const float*)d_in[12];
    const float* v2   = (const float*)d_in[13];
    const float* Wih0 = (const float*)d_in[14];
    const float* Whh0 = (const float*)d_in[15];
    const float* bih0 = (const float*)d_in[16];
    const float* bhh0 = (const float*)d_in[17];
    const float* Wih1 = (const float*)d_in[18];
    const float* Whh1 = (const float*)d_in[19];
    const float* bih1 = (const float*)d_in[20];
    const float* bhh1 = (const float*)d_in[21];
    const float* Wc   = (const float*)d_in[22];
    const float* bc   = (const float*)d_in[23];

    char* base = (char*)d_ws;
    // Aliasing: hist_g [0, 10.24 MB) dead after k_colsum; bpart
    // [10.24, 20.48 MB) written in k_part (after colsum), dead after k_place;
    // vh [0, 20.48 MB) written in k_gather (after k_place). Safe ordering.
    unsigned int* hist_g = (unsigned int*)base;                       // T*NBA*NPACK u32
    unsigned int* bpart  = (unsigned int*)(base + (size_t)T * NBA * NPACK * 4);
    __half*       vh     = (__half*)base;                             // T*N*64 f16
    char* p = base + (size_t)T * NBA * NPACK * 4 + (size_t)T * NBUK * CHUNKA * 4;
    __half* xh   = (__half*)p;              p += (size_t)T * N * 64 * 2;  // 20.5 MB
    int*   offs  = (int*)p;                 p += (size_t)(T * N + 1) * 4 + 12; // keep 16B align
    int*   dega  = (int*)p;                 p += (size_t)T * N * 4;
    float* dinv  = (float*)p;               p += (size_t)T * N * 4;
    float* alpha = (float*)p;               p += (size_t)T * N * 4;
    int*   tot   = (int*)p;                 p += (size_t)T * N * 4;   // warm sink
    int*   eidx  = (int*)p;                 p += (size_t)T * E * 4;   // 10.25 MB
    float* wpart = (float*)p;               p += (size_t)T * NBUK * N * 4; // 20.5 MB
    int*   bcnt  = (int*)p;                 p += (size_t)T * NBUK * NBUK * 4;
    float* pooled= (float*)p;               p += (size_t)T * 128 * 4;
    float* gx0_g = (float*)p;               p += (size_t)T * 512 * 4;
    __half* W1t  = (__half*)p;

    (void)hipMemsetAsync(pooled, 0, T * 128 * sizeof(float), stream);

    k_prepw<<<32, 256, 0, stream>>>(W1, W1t);
    dim3 gs(T, NBA);
    k_hist<<<gs, 1024, 0, stream>>>(edges, hist_g);
    k_colsum<<<(T * NPACK + 255) / 256, 256, 0, stream>>>(hist_g, dega, dinv);
    k_scanN<<<T, 1024, 0, stream>>>(dega, offs);
    k_cvt<<<(T * N * 16 + 255) / 256, 256, 0, stream>>>(x, dinv, xh);
    k_part<<<T * NBUK, 1024, 0, stream>>>(edges, dinv, bpart, bcnt, wpart);
    k_place<<<T * NBUK, 1024, 0, stream>>>(bpart, bcnt, offs, eidx);
    k_wred<<<(T * N + 255) / 256, 256, 0, stream>>>(wpart, dinv, alpha);
    k_gather<<<(T * N) / 4, 256, 0, stream>>>(eidx, offs, dinv, xh, vh);
    k_mfma_pool<<<8 * 40, 256, 0, stream>>>(vh, alpha, W1t, b1, g1, be1, m1, v1, pooled);

    k_warm<<<64, 256, 0, stream>>>(Whh0, Whh1, Wih1, (float*)tot);
    k_emb<<<T, 512, 0, stream>>>(pooled, W2, b2, g2, be2, m2, v2, Wih0, bih0, bhh0, gx0_g);
    k_head<<<1, 1024, 0, stream>>>(gx0_g, Whh0, Whh1, Wih1, bih1, bhh1, Wc, bc, (float*)d_out);
}